// Round 14
// baseline (459.613 us; speedup 1.0000x reference)
//
#include <hip/hip_runtime.h>

// GraphV1EmbLarge round 14:
//  - gemm2/gemm3: split-K x2 (grid (640,2), bf16 partials to Gb[0|1]) ->
//    1280 blocks = 5/CU, fixing the 2.5-blocks/CU wave quantization that
//    capped occupancy at 21% (r10 barriers / r11 tile both failed because
//    the real limiter was block-count starvation). Partial-add fused into
//    the gather (no combine pass, no atomics).
//  - gather: r10 uint4/128-thr form + 4-deep edge unroll + dual-buffer reads
//    (8 independent loads in flight; the neighbor loop is latency-bound).
// Round-13 baseline: 400us; gemm2 69us @ occupancy 21%.

#define N_NODES 10000
#define N_EDGES 80000
#define EMB_DIM 128
#define FEAT_DIM 63
#define IN_GNN 191
#define IN_STRIDE 192
#define H1 2048
#define H2 1024
#define NGRAPH 16
#define NCLS 2
#define PCHUNK 8

using ushort = unsigned short;
typedef __attribute__((ext_vector_type(8))) short s8b;   // 8 bf16 (4 VGPRs)
typedef __attribute__((ext_vector_type(4))) float f4v;   // 4 fp32 acc

__device__ __forceinline__ float us2f(ushort u) {
    union { unsigned int i; float f; } v; v.i = ((unsigned int)u) << 16; return v.f;
}
__device__ __forceinline__ ushort f2us(float f) {
    union { unsigned int i; float f; } v; v.f = f;
    unsigned int r = v.i + 0x7FFFu + ((v.i >> 16) & 1u);
    return (ushort)(r >> 16);
}
__device__ __forceinline__ float ldm(const void* p, long i, int md) {
    return (md == 1) ? us2f(((const ushort*)p)[i]) : ((const float*)p)[i];
}

__global__ void GraphV1EmbLarge_73864847556672_kernel() {}

// ---------------- zero + dtype detect (merged) ----------------
__global__ void k_prep0(int* __restrict__ a, int na, float* __restrict__ b, int nb,
                        const ushort* __restrict__ feats, int* __restrict__ mode) {
    int i = blockIdx.x * 256 + threadIdx.x;
    if (i < na) a[i] = 0;
    if (i < nb) b[i] = 0.f;
    if (blockIdx.x == 0 && threadIdx.x == 0) {
        int sane = 0;
        for (int j = 0; j < 256; j++) {
            ushort u = feats[j];
            int e = (u >> 7) & 0xFF;
            if (u == 0 || (e >= 97 && e <= 157)) sane++;
        }
        *mode = (sane >= 220) ? 1 : 2;
    }
}

__global__ void k_deg_i(const int* __restrict__ dst, int* __restrict__ cnt) {
    int e = blockIdx.x * blockDim.x + threadIdx.x;
    if (e < N_EDGES) atomicAdd(&cnt[dst[e]], 1);
}
__global__ void k_scan(const int* __restrict__ cnt, int* __restrict__ indptr,
                       float* __restrict__ dinv) {
    __shared__ int part[256];
    int t = threadIdx.x;
    int base = t * 40;
    int s = 0;
    for (int i = 0; i < 40; i++) { int idx = base + i; if (idx < N_NODES) s += cnt[idx]; }
    part[t] = s;
    __syncthreads();
    if (t == 0) {
        int run = 0;
        for (int i = 0; i < 256; i++) { int tmp = part[i]; part[i] = run; run += tmp; }
        indptr[N_NODES] = run;
    }
    __syncthreads();
    int run = part[t];
    for (int i = 0; i < 40; i++) {
        int idx = base + i;
        if (idx < N_NODES) {
            indptr[idx] = run; run += cnt[idx];
            dinv[idx] = rsqrtf((float)cnt[idx] + 1.0f);  // +1 self loop
        }
    }
}
// fill + starts (merged)
__global__ void k_fill(const int* __restrict__ src, const int* __restrict__ dst,
                       const int* __restrict__ indptr, int* __restrict__ cursor,
                       const float* __restrict__ dinv, int* __restrict__ ecol,
                       float* __restrict__ ewgt, const int* __restrict__ batch,
                       int* __restrict__ starts) {
    int b = blockIdx.x;
    if (b < 313) {
        int e = b * 256 + threadIdx.x;
        if (e >= N_EDGES) return;
        int d = dst[e], s = src[e];
        int slot = indptr[d] + atomicAdd(&cursor[d], 1);
        ecol[slot] = s;
        ewgt[slot] = dinv[s] * dinv[d];
    } else {
        int i = (b - 313) * 256 + threadIdx.x;
        if (i > N_NODES) return;
        int bc = (i < N_NODES) ? batch[i] : NGRAPH;
        int bp = (i == 0) ? -1 : batch[i - 1];
        for (int g = bp + 1; g <= bc; g++) starts[g] = i;
    }
}

// ---------------- conversions (tiles + x0 + biases in one launch) -----------
__device__ __forceinline__ void cvt_tile(const void* W, int K, int N, int Kp,
                                         ushort* Wt, int n0, int k0, int md) {
    __shared__ float tile[32][33];
    int tx = threadIdx.x, ty = threadIdx.y;
    for (int r = ty; r < 32; r += 8) {
        int k = k0 + r;
        tile[r][tx] = (k < K) ? ldm(W, (long)k * N + n0 + tx, md) : 0.f;
    }
    __syncthreads();
    for (int r = ty; r < 32; r += 8) {
        int nn = n0 + r, kk = k0 + tx;
        if (kk < Kp) Wt[(long)nn * Kp + kk] = f2us(tile[tx][r]);
    }
}

__global__ void k_cvt_all(const void* W1, const void* W2, const void* W3,
                          const void* h1, const void* h2, const void* h3,
                          ushort* W1t, ushort* W2t, ushort* W3t,
                          ushort* h1t, ushort* h2t, ushort* h3t,
                          const int* __restrict__ types, const void* emb,
                          const void* feats, ushort* __restrict__ x0,
                          const void* b1, const void* b2, const void* b3,
                          float* __restrict__ b1f, float* __restrict__ b2f,
                          float* __restrict__ b3f, const int* __restrict__ mode) {
    int md = *mode;
    int b = blockIdx.x;
    if (b < 384) {
        int t = b;        cvt_tile(W1, IN_GNN, H1, IN_STRIDE, W1t, (t % 64) * 32, (t / 64) * 32, md);
    } else if (b < 2432) {
        int t = b - 384;  cvt_tile(W2, H1, H2, H1, W2t, (t % 32) * 32, (t / 32) * 32, md);
    } else if (b < 3456) {
        int t = b - 2432; cvt_tile(W3, H2, H2, H2, W3t, (t % 32) * 32, (t / 32) * 32, md);
    } else if (b < 4480) {
        int t = b - 3456; cvt_tile(h1, H2, H2, H2, h1t, (t % 32) * 32, (t / 32) * 32, md);
    } else if (b < 5504) {
        int t = b - 4480; cvt_tile(h2, H2, H2, H2, h2t, (t % 32) * 32, (t / 32) * 32, md);
    } else if (b < 6016) {
        int t = b - 5504; cvt_tile(h3, H2, 512, H2, h3t, (t % 16) * 32, (t / 16) * 32, md);
    } else if (b < 16016) {
        int i = b - 6016;                       // node index
        int c = threadIdx.y * 32 + threadIdx.x; // 0..255
        if (c >= IN_STRIDE) return;
        float v = 0.f;
        if (c < EMB_DIM) v = ldm(emb, (long)types[i] * EMB_DIM + c, md);
        else if (c < IN_GNN) v = ldm(feats, (long)i * FEAT_DIM + (c - EMB_DIM), md);
        x0[(long)i * IN_STRIDE + c] = f2us(v);
    } else {
        int i = (b - 16016) * 256 + threadIdx.y * 32 + threadIdx.x;
        if (i < 2048) b1f[i] = ldm(b1, i, md);
        else if (i < 3072) b2f[i - 2048] = ldm(b2, (long)(i - 2048), md);
        else if (i < 4096) b3f[i - 3072] = ldm(b3, (long)(i - 3072), md);
    }
}

// ---------------- CSR gathers ----------------
__global__ void k_gather192(const ushort* __restrict__ H, const int* __restrict__ indptr,
                            const int* __restrict__ ecol, const float* __restrict__ ewgt,
                            const float* __restrict__ dinv, ushort* __restrict__ X) {
    int d = blockIdx.x;
    int c = threadIdx.x;  // 192
    float ds = dinv[d];
    float acc = us2f(H[(long)d * IN_STRIDE + c]) * ds * ds;
    int s0 = indptr[d], s1 = indptr[d + 1];
    int s = s0;
    for (; s + 1 < s1; s += 2) {
        int sa = ecol[s], sb = ecol[s + 1];
        float wa = ewgt[s], wb = ewgt[s + 1];
        float fa = us2f(H[(long)sa * IN_STRIDE + c]);
        float fb = us2f(H[(long)sb * IN_STRIDE + c]);
        acc += fa * wa + fb * wb;
    }
    if (s < s1) acc += us2f(H[(long)ecol[s] * IN_STRIDE + c]) * ewgt[s];
    X[(long)d * IN_STRIDE + c] = f2us(acc);
}

__device__ __forceinline__ void unpack8(uint4 u, float* f) {
    f[0] = us2f((ushort)(u.x & 0xffff)); f[1] = us2f((ushort)(u.x >> 16));
    f[2] = us2f((ushort)(u.y & 0xffff)); f[3] = us2f((ushort)(u.y >> 16));
    f[4] = us2f((ushort)(u.z & 0xffff)); f[5] = us2f((ushort)(u.z >> 16));
    f[6] = us2f((ushort)(u.w & 0xffff)); f[7] = us2f((ushort)(u.w >> 16));
}

// width-1024 gather over TWO bf16 split-K partial buffers (H and H+SOFF):
// X[d] = relu((P0[d]+P1[d])*dinv^2 + sum_e (P0[col]+P1[col])*wgt + bias).
// 128 thr x 8 cols (uint4); edge loop 4-deep (8 loads in flight).
__global__ void k_gather2(const ushort* __restrict__ H, const int* __restrict__ indptr,
                          const int* __restrict__ ecol, const float* __restrict__ ewgt,
                          const float* __restrict__ dinv, const float* __restrict__ bias,
                          ushort* __restrict__ X) {
    const long SOFF = (long)N_NODES * H2;
    int d = blockIdx.x;
    int c8 = threadIdx.x * 8;
    float ds = dinv[d];
    float a[8], f0[8], f1[8];
    {
        uint4 u1 = *(const uint4*)&H[(long)d * H2 + c8];
        uint4 u2 = *(const uint4*)&H[SOFF + (long)d * H2 + c8];
        unpack8(u1, f0);
        unpack8(u2, f1);
        float w0 = ds * ds;
#pragma unroll
        for (int r = 0; r < 8; r++) a[r] = (f0[r] + f1[r]) * w0;
    }
    int s0 = indptr[d], s1 = indptr[d + 1];
    int s = s0;
    for (; s + 3 < s1; s += 4) {
        int sc[4];
        float wv[4];
        uint4 u[8];
#pragma unroll
        for (int q = 0; q < 4; q++) { sc[q] = ecol[s + q]; wv[q] = ewgt[s + q]; }
#pragma unroll
        for (int q = 0; q < 4; q++) {
            u[2 * q] = *(const uint4*)&H[(long)sc[q] * H2 + c8];
            u[2 * q + 1] = *(const uint4*)&H[SOFF + (long)sc[q] * H2 + c8];
        }
#pragma unroll
        for (int q = 0; q < 4; q++) {
            unpack8(u[2 * q], f0);
            unpack8(u[2 * q + 1], f1);
#pragma unroll
            for (int r = 0; r < 8; r++) a[r] += (f0[r] + f1[r]) * wv[q];
        }
    }
    for (; s < s1; s++) {
        int sc = ecol[s];
        float wv = ewgt[s];
        uint4 u1 = *(const uint4*)&H[(long)sc * H2 + c8];
        uint4 u2 = *(const uint4*)&H[SOFF + (long)sc * H2 + c8];
        unpack8(u1, f0);
        unpack8(u2, f1);
#pragma unroll
        for (int r = 0; r < 8; r++) a[r] += (f0[r] + f1[r]) * wv;
    }
    uint4 o;
    unsigned int p0 = (unsigned int)f2us(fmaxf(a[0] + bias[c8 + 0], 0.f));
    unsigned int p1 = (unsigned int)f2us(fmaxf(a[1] + bias[c8 + 1], 0.f));
    unsigned int p2 = (unsigned int)f2us(fmaxf(a[2] + bias[c8 + 2], 0.f));
    unsigned int p3 = (unsigned int)f2us(fmaxf(a[3] + bias[c8 + 3], 0.f));
    unsigned int p4 = (unsigned int)f2us(fmaxf(a[4] + bias[c8 + 4], 0.f));
    unsigned int p5 = (unsigned int)f2us(fmaxf(a[5] + bias[c8 + 5], 0.f));
    unsigned int p6 = (unsigned int)f2us(fmaxf(a[6] + bias[c8 + 6], 0.f));
    unsigned int p7 = (unsigned int)f2us(fmaxf(a[7] + bias[c8 + 7], 0.f));
    o.x = p0 | (p1 << 16); o.y = p2 | (p3 << 16);
    o.z = p4 | (p5 << 16); o.w = p6 | (p7 << 16);
    *(uint4*)&X[(long)d * H2 + c8] = o;
}

// ---------------- MFMA bf16 GEMM: r10 core + split-K via blockIdx.y ---------
// grid (NB*80, nsplit). Split s handles k in [s*Ksub, (s+1)*Ksub), writes
// partials to C + s*M*N. XCD swizzle on x-dim; dbuf+prefetch+XOR swizzle.
__global__ __launch_bounds__(256) void k_mfma_gemm(
    const ushort* __restrict__ A, int lda, int M,
    const ushort* __restrict__ Wt, int ldb, int Ksub, int N,
    const float* __restrict__ bias, int relu,
    ushort* __restrict__ C, int NB) {
    __shared__ ushort As[2][128 * 32];
    __shared__ ushort Bs[2][128 * 32];
    int split = blockIdx.y;
    A += (long)split * Ksub;
    Wt += (long)split * Ksub;
    C += (long)split * M * N;
    int L = blockIdx.x;
    int i = L >> 3;
    int m_t = (L & 7) + (i / NB) * 8;
    int n_t = i % NB;
    int m0 = m_t * 128, n0 = n_t * 128;
    if (m0 >= M) return;
    int tid = threadIdx.x;
    int wave = tid >> 6, lane = tid & 63;
    int wm = (wave & 1) * 64, wn = (wave >> 1) * 64;
    int quad = lane >> 4, l16 = lane & 15;
    int srow = tid >> 2;
    int scol = (tid & 3) * 8;
    int swz = ((srow >> 1) & 3) << 3;
    int rwz = ((l16 >> 1) & 3) << 3;
    int wa0 = srow * 32 + (scol ^ swz);
    int wa1 = (64 + srow) * 32 + (scol ^ swz);

    f4v acc[4][4];
#pragma unroll
    for (int ii = 0; ii < 4; ii++)
#pragma unroll
        for (int jj = 0; jj < 4; jj++) acc[ii][jj] = (f4v)(0.f);

    int gm1 = m0 + srow;       if (gm1 >= M) gm1 = M - 1;
    int gm2 = m0 + 64 + srow;  if (gm2 >= M) gm2 = M - 1;
    const ushort* pa1 = A + (long)gm1 * lda + scol;
    const ushort* pa2 = A + (long)gm2 * lda + scol;
    const ushort* pb1 = Wt + (long)(n0 + srow) * ldb + scol;
    const ushort* pb2 = Wt + (long)(n0 + 64 + srow) * ldb + scol;

    int niter = Ksub >> 5;
    s8b va1 = *(const s8b*)pa1;
    s8b va2 = *(const s8b*)pa2;
    s8b vb1 = *(const s8b*)pb1;
    s8b vb2 = *(const s8b*)pb2;
    *(s8b*)&As[0][wa0] = va1;
    *(s8b*)&As[0][wa1] = va2;
    *(s8b*)&Bs[0][wa0] = vb1;
    *(s8b*)&Bs[0][wa1] = vb2;
    if (niter > 1) {
        pa1 += 32; pa2 += 32; pb1 += 32; pb2 += 32;
        va1 = *(const s8b*)pa1;
        va2 = *(const s8b*)pa2;
        vb1 = *(const s8b*)pb1;
        vb2 = *(const s8b*)pb2;
    }

    for (int it = 0; it < niter; it++) {
        int cur = it & 1;
        __syncthreads();
        if (it + 1 < niter) {
            int nxt = cur ^ 1;
            *(s8b*)&As[nxt][wa0] = va1;
            *(s8b*)&As[nxt][wa1] = va2;
            *(s8b*)&Bs[nxt][wa0] = vb1;
            *(s8b*)&Bs[nxt][wa1] = vb2;
            if (it + 2 < niter) {
                pa1 += 32; pa2 += 32; pb1 += 32; pb2 += 32;
                va1 = *(const s8b*)pa1;
                va2 = *(const s8b*)pa2;
                vb1 = *(const s8b*)pb1;
                vb2 = *(const s8b*)pb2;
            }
        }
        s8b a[4], b[4];
#pragma unroll
        for (int ii = 0; ii < 4; ii++)
            a[ii] = *(const s8b*)&As[cur][(wm + ii * 16 + l16) * 32 + (quad * 8 ^ rwz)];
#pragma unroll
        for (int jj = 0; jj < 4; jj++)
            b[jj] = *(const s8b*)&Bs[cur][(wn + jj * 16 + l16) * 32 + (quad * 8 ^ rwz)];
#pragma unroll
        for (int ii = 0; ii < 4; ii++)
#pragma unroll
            for (int jj = 0; jj < 4; jj++)
                acc[ii][jj] = __builtin_amdgcn_mfma_f32_16x16x32_bf16(a[ii], b[jj], acc[ii][jj], 0, 0, 0);
    }

#pragma unroll
    for (int ii = 0; ii < 4; ii++) {
        int row0 = m0 + wm + ii * 16 + quad * 4;
#pragma unroll
        for (int jj = 0; jj < 4; jj++) {
            int colc = n0 + wn + jj * 16 + l16;
            float bv = bias ? bias[colc] : 0.f;
#pragma unroll
            for (int r = 0; r < 4; r++) {
                int row = row0 + r;
                if (row < M) {
                    float v = acc[ii][jj][r] + bv;
                    if (relu) v = fmaxf(v, 0.f);
                    C[(long)row * N + colc] = f2us(v);
                }
            }
        }
    }
}

// ---------------- pool stage 1 ----------------
__global__ void k_pool_part(const ushort* __restrict__ x, const int* __restrict__ starts,
                            float* __restrict__ acc) {
    int g = blockIdx.x / PCHUNK, ch = blockIdx.x % PCHUNK;
    int c = blockIdx.y * 256 + threadIdx.x;
    int s0 = starts[g], s1 = starts[g + 1];
    int len = s1 - s0;
    int per = (len + PCHUNK - 1) / PCHUNK;
    int r0 = s0 + ch * per;
    int r1 = r0 + per; if (r1 > s1) r1 = s1;
    if (r0 >= r1) return;
    float sum = 0.f;
    for (int i = r0; i < r1; i++) sum += us2f(x[(long)i * H2 + c]);
    atomicAdd(&acc[g * H2 + c], sum);
}

// ---------------- MLP head: full-K fused MFMA (reduce+bias+relu inline) -----
__global__ __launch_bounds__(256) void k_head_full(const ushort* __restrict__ A,
                                                   const ushort* __restrict__ Wt,
                                                   const void* __restrict__ bias,
                                                   ushort* __restrict__ out, int N,
                                                   const int* __restrict__ mode) {
    __shared__ float red[4][16][16];
    int md = *mode;
    int n0 = blockIdx.x * 16;
    int wave = threadIdx.x >> 6, lane = threadIdx.x & 63;
    int l16 = lane & 15, quad = lane >> 4;
    int kbase = wave * 256;
    f4v acc = (f4v)(0.f);
#pragma unroll
    for (int kk = 0; kk < 256; kk += 32) {
        int k = kbase + kk + quad * 8;
        s8b a = *(const s8b*)&A[l16 * 1024 + k];
        s8b b = *(const s8b*)&Wt[(long)(n0 + l16) * 1024 + k];
        acc = __builtin_amdgcn_mfma_f32_16x16x32_bf16(a, b, acc, 0, 0, 0);
    }
#pragma unroll
    for (int r = 0; r < 4; r++) red[wave][quad * 4 + r][l16] = acc[r];
    __syncthreads();
    int row = threadIdx.x >> 4, col = threadIdx.x & 15;
    float s = red[0][row][col] + red[1][row][col] + red[2][row][col] + red[3][row][col];
    s = fmaxf(s + ldm(bias, (long)(n0 + col), md), 0.f);
    out[(long)row * N + n0 + col] = f2us(s);
}

__global__ __launch_bounds__(256) void k_head_full_pool(const float* __restrict__ pacc,
                                                        const int* __restrict__ starts,
                                                        const ushort* __restrict__ Wt,
                                                        const void* __restrict__ bias,
                                                        ushort* __restrict__ out, int N,
                                                        const int* __restrict__ mode) {
    __shared__ float red[4][16][16];
    int md = *mode;
    int n0 = blockIdx.x * 16;
    int wave = threadIdx.x >> 6, lane = threadIdx.x & 63;
    int l16 = lane & 15, quad = lane >> 4;
    int cnt = starts[l16 + 1] - starts[l16];
    float rc = 1.f / (float)(cnt > 0 ? cnt : 1);
    int kbase = wave * 256;
    f4v acc = (f4v)(0.f);
#pragma unroll
    for (int kk = 0; kk < 256; kk += 32) {
        int k = kbase + kk + quad * 8;
        s8b a;
        short* ap = (short*)&a;
#pragma unroll
        for (int j = 0; j < 8; j++) ap[j] = (short)f2us(pacc[l16 * 1024 + k + j] * rc);
        s8b b = *(const s8b*)&Wt[(long)(n0 + l16) * 1024 + k];
        acc = __builtin_amdgcn_mfma_f32_16x16x32_bf16(a, b, acc, 0, 0, 0);
    }
#pragma unroll
    for (int r = 0; r < 4; r++) red[wave][quad * 4 + r][l16] = acc[r];
    __syncthreads();
    int row = threadIdx.x >> 4, col = threadIdx.x & 15;
    float s = red[0][row][col] + red[1][row][col] + red[2][row][col] + red[3][row][col];
    s = fmaxf(s + ldm(bias, (long)(n0 + col), md), 0.f);
    out[(long)row * N + n0 + col] = f2us(s);
}

__global__ void k_head_out(const ushort* __restrict__ in, const void* __restrict__ W,
                           const void* __restrict__ b, void* __restrict__ out,
                           const int* __restrict__ mode) {
    int md = *mode;
    int row = blockIdx.x >> 1, cls = blockIdx.x & 1;
    int lane = threadIdx.x;
    float acc = 0.f;
    for (int k = lane; k < 512; k += 64)
        acc += us2f(in[row * 512 + k]) * ldm(W, (long)k * NCLS + cls, md);
#pragma unroll
    for (int off = 32; off > 0; off >>= 1) acc += __shfl_down(acc, off);
    if (lane == 0) {
        float v = acc + ldm(b, (long)cls, md);
        if (md == 1) ((ushort*)out)[row * NCLS + cls] = f2us(v);
        else ((float*)out)[row * NCLS + cls] = v;
    }
}

extern "C" void kernel_launch(void* const* d_in, const int* in_sizes, int n_in,
                              void* d_out, int out_size, void* d_ws, size_t ws_size,
                              hipStream_t stream) {
    static const int EXPECT[19] = {
        10000, 630000, 160000, 10000, 128000,
        391168, 2048, 2097152, 1024, 1048576, 1024,
        1048576, 1024, 1048576, 1024, 524288, 512, 1024, 2
    };
    if (n_in != 19) { hipMemsetAsync(d_out, 0x48, 64, stream); return; }
    for (int i = 0; i < 19; i++)
        if (in_sizes[i] != EXPECT[i]) { hipMemsetAsync(d_out, 0x50 + i, 64, stream); return; }
    if (ws_size < (size_t)105000000) { hipMemsetAsync(d_out, 0x49, 64, stream); return; }

    const int* node_types = (const int*)d_in[0];
    const void* other = d_in[1];
    const int* e_src = (const int*)d_in[2];
    const int* e_dst = e_src + N_EDGES;
    const int* batch = (const int*)d_in[3];

    // --- workspace carve-up (~103 MB; round-3 guard proved ws >= 110.4 MB) ---
    char* w = (char*)d_ws;
    int* mode = (int*)w;      w += 256;
    int* cnt = (int*)w;       w += 10240 * 4;
    int* cursor = (int*)w;    w += 10240 * 4;
    float* dinv = (float*)w;  w += 10240 * 4;
    int* starts = (int*)w;    w += 256;
    int* indptr = (int*)w;    w += 10240 * 4;
    int* ecol = (int*)w;      w += 81920 * 4;
    float* ewgt = (float*)w;  w += 81920 * 4;
    float* b1f = (float*)w;   w += 2048 * 4;
    float* b2f = (float*)w;   w += 1024 * 4;
    float* b3f = (float*)w;   w += 1024 * 4;
    float* pacc = (float*)w;  w += 16 * 1024 * 4;       // pool fp32 accumulator
    ushort* hA = (ushort*)w;  w += 16 * 1024 * 2;
    ushort* hB = (ushort*)w;  w += 16 * 1024 * 2;
    ushort* x0 = (ushort*)w;  w += 1920000 * 2;         // N x 192
    ushort* A1 = (ushort*)w;  w += 1920000 * 2;         // N x 192 aggregated
    ushort* W1t = (ushort*)w; w += 393216 * 2;          // 2048 x 192
    ushort* W2t = (ushort*)w; w += 2097152 * 2;         // 1024 x 2048
    ushort* W3t = (ushort*)w; w += 1048576 * 2;         // 1024 x 1024
    ushort* h1wt = (ushort*)w; w += 1048576 * 2;        // 1024 x 1024
    ushort* h2wt = (ushort*)w; w += 1048576 * 2;        // 1024 x 1024
    ushort* h3wt = (ushort*)w; w += 524288 * 2;         // 512 x 1024
    ushort* Hb = (ushort*)w;  w += 20480000 * 2;        // N x 2048 (x1; later x2|x3)
    ushort* Gb = (ushort*)w;  w += 2 * 10240000 * 2;    // 2 x (N x 1024) split-K partials
    ushort* x2 = Hb;
    ushort* x3 = Hb + (size_t)N_NODES * H2;

    hipGetLastError();
    k_prep0<<<80, 256, 0, stream>>>(cnt, 20480, pacc, NGRAPH * H2, (const ushort*)other, mode);
    hipError_t e0 = hipGetLastError();
    if (e0 != hipSuccess) { hipMemsetAsync(d_out, 0x46, 64, stream); return; }
    k_deg_i<<<(N_EDGES + 255) / 256, 256, 0, stream>>>(e_dst, cnt);
    k_scan<<<1, 256, 0, stream>>>(cnt, indptr, dinv);
    k_fill<<<313 + 40, 256, 0, stream>>>(e_src, e_dst, indptr, cursor, dinv, ecol, ewgt, batch, starts);

    // conversions: weight tiles + x0 + biases in one launch
    k_cvt_all<<<16032, dim3(32, 8), 0, stream>>>(d_in[5], d_in[7], d_in[9], d_in[11], d_in[13], d_in[15],
                                                 W1t, W2t, W3t, h1wt, h2wt, h3wt,
                                                 node_types, d_in[4], other, x0,
                                                 d_in[6], d_in[8], d_in[10], b1f, b2f, b3f, mode);

    // layer 1: aggregate x0 (width 192) then GEMM 192->2048 + bias + relu (no split)
    k_gather192<<<N_NODES, IN_STRIDE, 0, stream>>>(x0, indptr, ecol, ewgt, dinv, A1);
    k_mfma_gemm<<<dim3(16 * 80, 1), 256, 0, stream>>>(A1, IN_STRIDE, N_NODES, W1t, IN_STRIDE, IN_STRIDE, H1, b1f, 1, Hb, 16);

    // layer 2: GEMM 2048->1024 split-K x2 (partials), gather fuses the add
    k_mfma_gemm<<<dim3(8 * 80, 2), 256, 0, stream>>>(Hb, H1, N_NODES, W2t, H1, H1 / 2, H2, nullptr, 0, Gb, 8);
    k_gather2<<<N_NODES, 128, 0, stream>>>(Gb, indptr, ecol, ewgt, dinv, b2f, x2);

    // layer 3: GEMM 1024->1024 split-K x2, gather fuses the add
    k_mfma_gemm<<<dim3(8 * 80, 2), 256, 0, stream>>>(x2, H2, N_NODES, W3t, H2, H2 / 2, H2, nullptr, 0, Gb, 8);
    k_gather2<<<N_NODES, 128, 0, stream>>>(Gb, indptr, ecol, ewgt, dinv, b3f, x3);

    // pool partials; mean-normalize fused into head layer 1
    k_pool_part<<<dim3(NGRAPH * PCHUNK, H2 / 256), 256, 0, stream>>>(x3, starts, pacc);

    // MLP head: full-K fused per layer
    k_head_full_pool<<<64, 256, 0, stream>>>(pacc, starts, h1wt, d_in[12], hA, 1024, mode);
    k_head_full<<<64, 256, 0, stream>>>(hA, h2wt, d_in[14], hB, 1024, mode);
    k_head_full<<<32, 256, 0, stream>>>(hB, h3wt, d_in[16], hA, 512, mode);
    k_head_out<<<NGRAPH * NCLS, 64, 0, stream>>>(hA, d_in[17], d_in[18], d_out, mode);

    hipError_t e1 = hipGetLastError();
    if (e1 != hipSuccess) hipMemsetAsync(d_out, 0x47, 64, stream);
}

// Round 15
// 389.462 us; speedup vs baseline: 1.1801x; 1.1801x over previous
//
#include <hip/hip_runtime.h>

// GraphV1EmbLarge round 15: REVERT to round-13 (399.8us, best known) after
// r14's split-K regression (459us: occupancy rose only 25%, 2x partial
// writes + dual-buffer gather reads). One safe delta: PCHUNK 8->32 (pool
// stage-1 parallelism 512->2048 blocks).
// GEMM plateau is now established: 5 independent attacks, only the
// bank-conflict fix (r9) moved it. Gathers likewise plateaued.

#define N_NODES 10000
#define N_EDGES 80000
#define EMB_DIM 128
#define FEAT_DIM 63
#define IN_GNN 191
#define IN_STRIDE 192
#define H1 2048
#define H2 1024
#define NGRAPH 16
#define NCLS 2
#define PCHUNK 32

using ushort = unsigned short;
typedef __attribute__((ext_vector_type(8))) short s8b;   // 8 bf16 (4 VGPRs)
typedef __attribute__((ext_vector_type(4))) float f4v;   // 4 fp32 acc

__device__ __forceinline__ float us2f(ushort u) {
    union { unsigned int i; float f; } v; v.i = ((unsigned int)u) << 16; return v.f;
}
__device__ __forceinline__ ushort f2us(float f) {
    union { unsigned int i; float f; } v; v.f = f;
    unsigned int r = v.i + 0x7FFFu + ((v.i >> 16) & 1u);
    return (ushort)(r >> 16);
}
__device__ __forceinline__ float ldm(const void* p, long i, int md) {
    return (md == 1) ? us2f(((const ushort*)p)[i]) : ((const float*)p)[i];
}

__global__ void GraphV1EmbLarge_73864847556672_kernel() {}

// ---------------- zero + dtype detect (merged) ----------------
__global__ void k_prep0(int* __restrict__ a, int na, float* __restrict__ b, int nb,
                        const ushort* __restrict__ feats, int* __restrict__ mode) {
    int i = blockIdx.x * 256 + threadIdx.x;
    if (i < na) a[i] = 0;
    if (i < nb) b[i] = 0.f;
    if (blockIdx.x == 0 && threadIdx.x == 0) {
        int sane = 0;
        for (int j = 0; j < 256; j++) {
            ushort u = feats[j];
            int e = (u >> 7) & 0xFF;
            if (u == 0 || (e >= 97 && e <= 157)) sane++;
        }
        *mode = (sane >= 220) ? 1 : 2;
    }
}

__global__ void k_deg_i(const int* __restrict__ dst, int* __restrict__ cnt) {
    int e = blockIdx.x * blockDim.x + threadIdx.x;
    if (e < N_EDGES) atomicAdd(&cnt[dst[e]], 1);
}
__global__ void k_scan(const int* __restrict__ cnt, int* __restrict__ indptr,
                       float* __restrict__ dinv) {
    __shared__ int part[256];
    int t = threadIdx.x;
    int base = t * 40;
    int s = 0;
    for (int i = 0; i < 40; i++) { int idx = base + i; if (idx < N_NODES) s += cnt[idx]; }
    part[t] = s;
    __syncthreads();
    if (t == 0) {
        int run = 0;
        for (int i = 0; i < 256; i++) { int tmp = part[i]; part[i] = run; run += tmp; }
        indptr[N_NODES] = run;
    }
    __syncthreads();
    int run = part[t];
    for (int i = 0; i < 40; i++) {
        int idx = base + i;
        if (idx < N_NODES) {
            indptr[idx] = run; run += cnt[idx];
            dinv[idx] = rsqrtf((float)cnt[idx] + 1.0f);  // +1 self loop
        }
    }
}
// fill + starts (merged)
__global__ void k_fill(const int* __restrict__ src, const int* __restrict__ dst,
                       const int* __restrict__ indptr, int* __restrict__ cursor,
                       const float* __restrict__ dinv, int* __restrict__ ecol,
                       float* __restrict__ ewgt, const int* __restrict__ batch,
                       int* __restrict__ starts) {
    int b = blockIdx.x;
    if (b < 313) {
        int e = b * 256 + threadIdx.x;
        if (e >= N_EDGES) return;
        int d = dst[e], s = src[e];
        int slot = indptr[d] + atomicAdd(&cursor[d], 1);
        ecol[slot] = s;
        ewgt[slot] = dinv[s] * dinv[d];
    } else {
        int i = (b - 313) * 256 + threadIdx.x;
        if (i > N_NODES) return;
        int bc = (i < N_NODES) ? batch[i] : NGRAPH;
        int bp = (i == 0) ? -1 : batch[i - 1];
        for (int g = bp + 1; g <= bc; g++) starts[g] = i;
    }
}

// ---------------- conversions (tiles + x0 + biases in one launch) -----------
__device__ __forceinline__ void cvt_tile(const void* W, int K, int N, int Kp,
                                         ushort* Wt, int n0, int k0, int md) {
    __shared__ float tile[32][33];
    int tx = threadIdx.x, ty = threadIdx.y;
    for (int r = ty; r < 32; r += 8) {
        int k = k0 + r;
        tile[r][tx] = (k < K) ? ldm(W, (long)k * N + n0 + tx, md) : 0.f;
    }
    __syncthreads();
    for (int r = ty; r < 32; r += 8) {
        int nn = n0 + r, kk = k0 + tx;
        if (kk < Kp) Wt[(long)nn * Kp + kk] = f2us(tile[tx][r]);
    }
}

__global__ void k_cvt_all(const void* W1, const void* W2, const void* W3,
                          const void* h1, const void* h2, const void* h3,
                          ushort* W1t, ushort* W2t, ushort* W3t,
                          ushort* h1t, ushort* h2t, ushort* h3t,
                          const int* __restrict__ types, const void* emb,
                          const void* feats, ushort* __restrict__ x0,
                          const void* b1, const void* b2, const void* b3,
                          float* __restrict__ b1f, float* __restrict__ b2f,
                          float* __restrict__ b3f, const int* __restrict__ mode) {
    int md = *mode;
    int b = blockIdx.x;
    if (b < 384) {
        int t = b;        cvt_tile(W1, IN_GNN, H1, IN_STRIDE, W1t, (t % 64) * 32, (t / 64) * 32, md);
    } else if (b < 2432) {
        int t = b - 384;  cvt_tile(W2, H1, H2, H1, W2t, (t % 32) * 32, (t / 32) * 32, md);
    } else if (b < 3456) {
        int t = b - 2432; cvt_tile(W3, H2, H2, H2, W3t, (t % 32) * 32, (t / 32) * 32, md);
    } else if (b < 4480) {
        int t = b - 3456; cvt_tile(h1, H2, H2, H2, h1t, (t % 32) * 32, (t / 32) * 32, md);
    } else if (b < 5504) {
        int t = b - 4480; cvt_tile(h2, H2, H2, H2, h2t, (t % 32) * 32, (t / 32) * 32, md);
    } else if (b < 6016) {
        int t = b - 5504; cvt_tile(h3, H2, 512, H2, h3t, (t % 16) * 32, (t / 16) * 32, md);
    } else if (b < 16016) {
        int i = b - 6016;                       // node index
        int c = threadIdx.y * 32 + threadIdx.x; // 0..255
        if (c >= IN_STRIDE) return;
        float v = 0.f;
        if (c < EMB_DIM) v = ldm(emb, (long)types[i] * EMB_DIM + c, md);
        else if (c < IN_GNN) v = ldm(feats, (long)i * FEAT_DIM + (c - EMB_DIM), md);
        x0[(long)i * IN_STRIDE + c] = f2us(v);
    } else {
        int i = (b - 16016) * 256 + threadIdx.y * 32 + threadIdx.x;
        if (i < 2048) b1f[i] = ldm(b1, i, md);
        else if (i < 3072) b2f[i - 2048] = ldm(b2, (long)(i - 2048), md);
        else if (i < 4096) b3f[i - 3072] = ldm(b3, (long)(i - 3072), md);
    }
}

// ---------------- CSR gathers ----------------
__global__ void k_gather192(const ushort* __restrict__ H, const int* __restrict__ indptr,
                            const int* __restrict__ ecol, const float* __restrict__ ewgt,
                            const float* __restrict__ dinv, ushort* __restrict__ X) {
    int d = blockIdx.x;
    int c = threadIdx.x;  // 192
    float ds = dinv[d];
    float acc = us2f(H[(long)d * IN_STRIDE + c]) * ds * ds;
    int s0 = indptr[d], s1 = indptr[d + 1];
    int s = s0;
    for (; s + 1 < s1; s += 2) {
        int sa = ecol[s], sb = ecol[s + 1];
        float wa = ewgt[s], wb = ewgt[s + 1];
        float fa = us2f(H[(long)sa * IN_STRIDE + c]);
        float fb = us2f(H[(long)sb * IN_STRIDE + c]);
        acc += fa * wa + fb * wb;
    }
    if (s < s1) acc += us2f(H[(long)ecol[s] * IN_STRIDE + c]) * ewgt[s];
    X[(long)d * IN_STRIDE + c] = f2us(acc);
}

// width-1024 gather, XCD-sliced (r13): block L -> node L>>3, slice (L&7)*128.
__global__ __launch_bounds__(64) void k_gather_slice(
    const ushort* __restrict__ H, const int* __restrict__ indptr,
    const int* __restrict__ ecol, const float* __restrict__ ewgt,
    const float* __restrict__ dinv, const float* __restrict__ bias,
    ushort* __restrict__ X) {
    int L = blockIdx.x;
    int d = L >> 3;
    int c2 = (L & 7) * 128 + threadIdx.x * 2;   // 2 cols/lane, 4B loads
    float ds = dinv[d];
    float w0 = ds * ds;
    unsigned int u = *(const unsigned int*)&H[(long)d * H2 + c2];
    float a0 = us2f((ushort)(u & 0xffff)) * w0;
    float a1 = us2f((ushort)(u >> 16)) * w0;
    int s0 = indptr[d], s1 = indptr[d + 1];
    int s = s0;
    for (; s + 1 < s1; s += 2) {
        int sa = ecol[s], sb = ecol[s + 1];
        float wa = ewgt[s], wb = ewgt[s + 1];
        unsigned int ua = *(const unsigned int*)&H[(long)sa * H2 + c2];
        unsigned int ub = *(const unsigned int*)&H[(long)sb * H2 + c2];
        a0 += us2f((ushort)(ua & 0xffff)) * wa + us2f((ushort)(ub & 0xffff)) * wb;
        a1 += us2f((ushort)(ua >> 16)) * wa + us2f((ushort)(ub >> 16)) * wb;
    }
    if (s < s1) {
        unsigned int ua = *(const unsigned int*)&H[(long)ecol[s] * H2 + c2];
        float wa = ewgt[s];
        a0 += us2f((ushort)(ua & 0xffff)) * wa;
        a1 += us2f((ushort)(ua >> 16)) * wa;
    }
    unsigned int o = (unsigned int)f2us(fmaxf(a0 + bias[c2], 0.f))
                   | ((unsigned int)f2us(fmaxf(a1 + bias[c2 + 1], 0.f)) << 16);
    *(unsigned int*)&X[(long)d * H2 + c2] = o;
}

// ---------------- MFMA bf16 GEMM: round-10/12 proven config -----------------
__global__ __launch_bounds__(256) void k_mfma_gemm(
    const ushort* __restrict__ A, int lda, int M,
    const ushort* __restrict__ Wt, int K, int N,
    const float* __restrict__ bias, int relu,
    ushort* __restrict__ C, int NB) {
    __shared__ ushort As[2][128 * 32];
    __shared__ ushort Bs[2][128 * 32];
    int L = blockIdx.x;
    int i = L >> 3;
    int m_t = (L & 7) + (i / NB) * 8;
    int n_t = i % NB;
    int m0 = m_t * 128, n0 = n_t * 128;
    if (m0 >= M) return;
    int tid = threadIdx.x;
    int wave = tid >> 6, lane = tid & 63;
    int wm = (wave & 1) * 64, wn = (wave >> 1) * 64;
    int quad = lane >> 4, l16 = lane & 15;
    int srow = tid >> 2;
    int scol = (tid & 3) * 8;
    int swz = ((srow >> 1) & 3) << 3;
    int rwz = ((l16 >> 1) & 3) << 3;
    int wa0 = srow * 32 + (scol ^ swz);
    int wa1 = (64 + srow) * 32 + (scol ^ swz);

    f4v acc[4][4];
#pragma unroll
    for (int ii = 0; ii < 4; ii++)
#pragma unroll
        for (int jj = 0; jj < 4; jj++) acc[ii][jj] = (f4v)(0.f);

    int gm1 = m0 + srow;       if (gm1 >= M) gm1 = M - 1;
    int gm2 = m0 + 64 + srow;  if (gm2 >= M) gm2 = M - 1;
    const ushort* pa1 = A + (long)gm1 * lda + scol;
    const ushort* pa2 = A + (long)gm2 * lda + scol;
    const ushort* pb1 = Wt + (long)(n0 + srow) * K + scol;
    const ushort* pb2 = Wt + (long)(n0 + 64 + srow) * K + scol;

    int niter = K >> 5;
    s8b va1 = *(const s8b*)pa1;
    s8b va2 = *(const s8b*)pa2;
    s8b vb1 = *(const s8b*)pb1;
    s8b vb2 = *(const s8b*)pb2;
    *(s8b*)&As[0][wa0] = va1;
    *(s8b*)&As[0][wa1] = va2;
    *(s8b*)&Bs[0][wa0] = vb1;
    *(s8b*)&Bs[0][wa1] = vb2;
    if (niter > 1) {
        pa1 += 32; pa2 += 32; pb1 += 32; pb2 += 32;
        va1 = *(const s8b*)pa1;
        va2 = *(const s8b*)pa2;
        vb1 = *(const s8b*)pb1;
        vb2 = *(const s8b*)pb2;
    }

    for (int it = 0; it < niter; it++) {
        int cur = it & 1;
        __syncthreads();
        if (it + 1 < niter) {
            int nxt = cur ^ 1;
            *(s8b*)&As[nxt][wa0] = va1;
            *(s8b*)&As[nxt][wa1] = va2;
            *(s8b*)&Bs[nxt][wa0] = vb1;
            *(s8b*)&Bs[nxt][wa1] = vb2;
            if (it + 2 < niter) {
                pa1 += 32; pa2 += 32; pb1 += 32; pb2 += 32;
                va1 = *(const s8b*)pa1;
                va2 = *(const s8b*)pa2;
                vb1 = *(const s8b*)pb1;
                vb2 = *(const s8b*)pb2;
            }
        }
        s8b a[4], b[4];
#pragma unroll
        for (int ii = 0; ii < 4; ii++)
            a[ii] = *(const s8b*)&As[cur][(wm + ii * 16 + l16) * 32 + (quad * 8 ^ rwz)];
#pragma unroll
        for (int jj = 0; jj < 4; jj++)
            b[jj] = *(const s8b*)&Bs[cur][(wn + jj * 16 + l16) * 32 + (quad * 8 ^ rwz)];
#pragma unroll
        for (int ii = 0; ii < 4; ii++)
#pragma unroll
            for (int jj = 0; jj < 4; jj++)
                acc[ii][jj] = __builtin_amdgcn_mfma_f32_16x16x32_bf16(a[ii], b[jj], acc[ii][jj], 0, 0, 0);
    }

#pragma unroll
    for (int ii = 0; ii < 4; ii++) {
        int row0 = m0 + wm + ii * 16 + quad * 4;
#pragma unroll
        for (int jj = 0; jj < 4; jj++) {
            int colc = n0 + wn + jj * 16 + l16;
            float bv = bias ? bias[colc] : 0.f;
#pragma unroll
            for (int r = 0; r < 4; r++) {
                int row = row0 + r;
                if (row < M) {
                    float v = acc[ii][jj][r] + bv;
                    if (relu) v = fmaxf(v, 0.f);
                    C[(long)row * N + colc] = f2us(v);
                }
            }
        }
    }
}

// ---------------- pool stage 1 (PCHUNK=32: 2048 blocks) ----------------
__global__ void k_pool_part(const ushort* __restrict__ x, const int* __restrict__ starts,
                            float* __restrict__ acc) {
    int g = blockIdx.x / PCHUNK, ch = blockIdx.x % PCHUNK;
    int c = blockIdx.y * 256 + threadIdx.x;
    int s0 = starts[g], s1 = starts[g + 1];
    int len = s1 - s0;
    int per = (len + PCHUNK - 1) / PCHUNK;
    int r0 = s0 + ch * per;
    int r1 = r0 + per; if (r1 > s1) r1 = s1;
    if (r0 >= r1) return;
    float sum = 0.f;
    for (int i = r0; i < r1; i++) sum += us2f(x[(long)i * H2 + c]);
    atomicAdd(&acc[g * H2 + c], sum);
}

// ---------------- MLP head: full-K fused MFMA (reduce+bias+relu inline) -----
__global__ __launch_bounds__(256) void k_head_full(const ushort* __restrict__ A,
                                                   const ushort* __restrict__ Wt,
                                                   const void* __restrict__ bias,
                                                   ushort* __restrict__ out, int N,
                                                   const int* __restrict__ mode) {
    __shared__ float red[4][16][16];
    int md = *mode;
    int n0 = blockIdx.x * 16;
    int wave = threadIdx.x >> 6, lane = threadIdx.x & 63;
    int l16 = lane & 15, quad = lane >> 4;
    int kbase = wave * 256;
    f4v acc = (f4v)(0.f);
#pragma unroll
    for (int kk = 0; kk < 256; kk += 32) {
        int k = kbase + kk + quad * 8;
        s8b a = *(const s8b*)&A[l16 * 1024 + k];
        s8b b = *(const s8b*)&Wt[(long)(n0 + l16) * 1024 + k];
        acc = __builtin_amdgcn_mfma_f32_16x16x32_bf16(a, b, acc, 0, 0, 0);
    }
#pragma unroll
    for (int r = 0; r < 4; r++) red[wave][quad * 4 + r][l16] = acc[r];
    __syncthreads();
    int row = threadIdx.x >> 4, col = threadIdx.x & 15;
    float s = red[0][row][col] + red[1][row][col] + red[2][row][col] + red[3][row][col];
    s = fmaxf(s + ldm(bias, (long)(n0 + col), md), 0.f);
    out[(long)row * N + n0 + col] = f2us(s);
}

__global__ __launch_bounds__(256) void k_head_full_pool(const float* __restrict__ pacc,
                                                        const int* __restrict__ starts,
                                                        const ushort* __restrict__ Wt,
                                                        const void* __restrict__ bias,
                                                        ushort* __restrict__ out, int N,
                                                        const int* __restrict__ mode) {
    __shared__ float red[4][16][16];
    int md = *mode;
    int n0 = blockIdx.x * 16;
    int wave = threadIdx.x >> 6, lane = threadIdx.x & 63;
    int l16 = lane & 15, quad = lane >> 4;
    int cnt = starts[l16 + 1] - starts[l16];
    float rc = 1.f / (float)(cnt > 0 ? cnt : 1);
    int kbase = wave * 256;
    f4v acc = (f4v)(0.f);
#pragma unroll
    for (int kk = 0; kk < 256; kk += 32) {
        int k = kbase + kk + quad * 8;
        s8b a;
        short* ap = (short*)&a;
#pragma unroll
        for (int j = 0; j < 8; j++) ap[j] = (short)f2us(pacc[l16 * 1024 + k + j] * rc);
        s8b b = *(const s8b*)&Wt[(long)(n0 + l16) * 1024 + k];
        acc = __builtin_amdgcn_mfma_f32_16x16x32_bf16(a, b, acc, 0, 0, 0);
    }
#pragma unroll
    for (int r = 0; r < 4; r++) red[wave][quad * 4 + r][l16] = acc[r];
    __syncthreads();
    int row = threadIdx.x >> 4, col = threadIdx.x & 15;
    float s = red[0][row][col] + red[1][row][col] + red[2][row][col] + red[3][row][col];
    s = fmaxf(s + ldm(bias, (long)(n0 + col), md), 0.f);
    out[(long)row * N + n0 + col] = f2us(s);
}

__global__ void k_head_out(const ushort* __restrict__ in, const void* __restrict__ W,
                           const void* __restrict__ b, void* __restrict__ out,
                           const int* __restrict__ mode) {
    int md = *mode;
    int row = blockIdx.x >> 1, cls = blockIdx.x & 1;
    int lane = threadIdx.x;
    float acc = 0.f;
    for (int k = lane; k < 512; k += 64)
        acc += us2f(in[row * 512 + k]) * ldm(W, (long)k * NCLS + cls, md);
#pragma unroll
    for (int off = 32; off > 0; off >>= 1) acc += __shfl_down(acc, off);
    if (lane == 0) {
        float v = acc + ldm(b, (long)cls, md);
        if (md == 1) ((ushort*)out)[row * NCLS + cls] = f2us(v);
        else ((float*)out)[row * NCLS + cls] = v;
    }
}

extern "C" void kernel_launch(void* const* d_in, const int* in_sizes, int n_in,
                              void* d_out, int out_size, void* d_ws, size_t ws_size,
                              hipStream_t stream) {
    static const int EXPECT[19] = {
        10000, 630000, 160000, 10000, 128000,
        391168, 2048, 2097152, 1024, 1048576, 1024,
        1048576, 1024, 1048576, 1024, 524288, 512, 1024, 2
    };
    if (n_in != 19) { hipMemsetAsync(d_out, 0x48, 64, stream); return; }
    for (int i = 0; i < 19; i++)
        if (in_sizes[i] != EXPECT[i]) { hipMemsetAsync(d_out, 0x50 + i, 64, stream); return; }
    if (ws_size < (size_t)90000000) { hipMemsetAsync(d_out, 0x49, 64, stream); return; }

    const int* node_types = (const int*)d_in[0];
    const void* other = d_in[1];
    const int* e_src = (const int*)d_in[2];
    const int* e_dst = e_src + N_EDGES;
    const int* batch = (const int*)d_in[3];

    // --- workspace carve-up (~83 MB) ---
    char* w = (char*)d_ws;
    int* mode = (int*)w;      w += 256;
    int* cnt = (int*)w;       w += 10240 * 4;
    int* cursor = (int*)w;    w += 10240 * 4;
    float* dinv = (float*)w;  w += 10240 * 4;
    int* starts = (int*)w;    w += 256;
    int* indptr = (int*)w;    w += 10240 * 4;
    int* ecol = (int*)w;      w += 81920 * 4;
    float* ewgt = (float*)w;  w += 81920 * 4;
    float* b1f = (float*)w;   w += 2048 * 4;
    float* b2f = (float*)w;   w += 1024 * 4;
    float* b3f = (float*)w;   w += 1024 * 4;
    float* pacc = (float*)w;  w += 16 * 1024 * 4;       // pool fp32 accumulator
    ushort* hA = (ushort*)w;  w += 16 * 1024 * 2;
    ushort* hB = (ushort*)w;  w += 16 * 1024 * 2;
    ushort* x0 = (ushort*)w;  w += 1920000 * 2;         // N x 192
    ushort* A1 = (ushort*)w;  w += 1920000 * 2;         // N x 192 aggregated
    ushort* W1t = (ushort*)w; w += 393216 * 2;          // 2048 x 192
    ushort* W2t = (ushort*)w; w += 2097152 * 2;         // 1024 x 2048
    ushort* W3t = (ushort*)w; w += 1048576 * 2;         // 1024 x 1024
    ushort* h1wt = (ushort*)w; w += 1048576 * 2;        // 1024 x 1024
    ushort* h2wt = (ushort*)w; w += 1048576 * 2;        // 1024 x 1024
    ushort* h3wt = (ushort*)w; w += 524288 * 2;         // 512 x 1024
    ushort* Hb = (ushort*)w;  w += 20480000 * 2;        // N x 2048 (x1; later x2|x3)
    ushort* Gb = (ushort*)w;  w += 10240000 * 2;        // N x 1024 (gemm2/3 out)
    ushort* x2 = Hb;
    ushort* x3 = Hb + (size_t)N_NODES * H2;

    hipGetLastError();
    k_prep0<<<80, 256, 0, stream>>>(cnt, 20480, pacc, NGRAPH * H2, (const ushort*)other, mode);
    hipError_t e0 = hipGetLastError();
    if (e0 != hipSuccess) { hipMemsetAsync(d_out, 0x46, 64, stream); return; }
    k_deg_i<<<(N_EDGES + 255) / 256, 256, 0, stream>>>(e_dst, cnt);
    k_scan<<<1, 256, 0, stream>>>(cnt, indptr, dinv);
    k_fill<<<313 + 40, 256, 0, stream>>>(e_src, e_dst, indptr, cursor, dinv, ecol, ewgt, batch, starts);

    // conversions: weight tiles + x0 + biases in one launch
    k_cvt_all<<<16032, dim3(32, 8), 0, stream>>>(d_in[5], d_in[7], d_in[9], d_in[11], d_in[13], d_in[15],
                                                 W1t, W2t, W3t, h1wt, h2wt, h3wt,
                                                 node_types, d_in[4], other, x0,
                                                 d_in[6], d_in[8], d_in[10], b1f, b2f, b3f, mode);

    // layer 1: aggregate x0 (width 192) then GEMM 192->2048 + bias + relu
    k_gather192<<<N_NODES, IN_STRIDE, 0, stream>>>(x0, indptr, ecol, ewgt, dinv, A1);
    k_mfma_gemm<<<16 * 80, 256, 0, stream>>>(A1, IN_STRIDE, N_NODES, W1t, IN_STRIDE, H1, b1f, 1, Hb, 16);

    // layer 2: GEMM 2048->1024, then XCD-sliced gather + bias + relu
    k_mfma_gemm<<<8 * 80, 256, 0, stream>>>(Hb, H1, N_NODES, W2t, H1, H2, nullptr, 0, Gb, 8);
    k_gather_slice<<<N_NODES * 8, 64, 0, stream>>>(Gb, indptr, ecol, ewgt, dinv, b2f, x2);

    // layer 3: GEMM 1024->1024, then XCD-sliced gather + bias + relu
    k_mfma_gemm<<<8 * 80, 256, 0, stream>>>(x2, H2, N_NODES, W3t, H2, H2, nullptr, 0, Gb, 8);
    k_gather_slice<<<N_NODES * 8, 64, 0, stream>>>(Gb, indptr, ecol, ewgt, dinv, b3f, x3);

    // pool partials; mean-normalize fused into head layer 1
    k_pool_part<<<dim3(NGRAPH * PCHUNK, H2 / 256), 256, 0, stream>>>(x3, starts, pacc);

    // MLP head: full-K fused per layer
    k_head_full_pool<<<64, 256, 0, stream>>>(pacc, starts, h1wt, d_in[12], hA, 1024, mode);
    k_head_full<<<64, 256, 0, stream>>>(hA, h2wt, d_in[14], hB, 1024, mode);
    k_head_full<<<32, 256, 0, stream>>>(hB, h3wt, d_in[16], hA, 512, mode);
    k_head_out<<<NGRAPH * NCLS, 64, 0, stream>>>(hA, d_in[17], d_in[18], d_out, mode);

    hipError_t e1 = hipGetLastError();
    if (e1 != hipSuccess) hipMemsetAsync(d_out, 0x47, 64, stream);
}

// Round 16
// 386.455 us; speedup vs baseline: 1.1893x; 1.0078x over previous
//
#include <hip/hip_runtime.h>

// GraphV1EmbLarge round 16: r15 frozen (389.5us best) + ONE change:
// k_gather192 rebuilt edge-parallel: 8 edge-groups x 24 col-chunks (uint4,
// 16B/lane vs old 2B/lane), LDS partial reduce. Old form was the last
// never-tuned kernel: scalar-width loads + deg/2 dependent chain.
// Established plateaus: gemm2 69us (5 attacks, only r9 conflict-fix moved it),
// gathers (r13/r14), head (r13). PCHUNK=32 (r15 win).

#define N_NODES 10000
#define N_EDGES 80000
#define EMB_DIM 128
#define FEAT_DIM 63
#define IN_GNN 191
#define IN_STRIDE 192
#define H1 2048
#define H2 1024
#define NGRAPH 16
#define NCLS 2
#define PCHUNK 32

using ushort = unsigned short;
typedef __attribute__((ext_vector_type(8))) short s8b;   // 8 bf16 (4 VGPRs)
typedef __attribute__((ext_vector_type(4))) float f4v;   // 4 fp32 acc

__device__ __forceinline__ float us2f(ushort u) {
    union { unsigned int i; float f; } v; v.i = ((unsigned int)u) << 16; return v.f;
}
__device__ __forceinline__ ushort f2us(float f) {
    union { unsigned int i; float f; } v; v.f = f;
    unsigned int r = v.i + 0x7FFFu + ((v.i >> 16) & 1u);
    return (ushort)(r >> 16);
}
__device__ __forceinline__ float ldm(const void* p, long i, int md) {
    return (md == 1) ? us2f(((const ushort*)p)[i]) : ((const float*)p)[i];
}

__global__ void GraphV1EmbLarge_73864847556672_kernel() {}

// ---------------- zero + dtype detect (merged) ----------------
__global__ void k_prep0(int* __restrict__ a, int na, float* __restrict__ b, int nb,
                        const ushort* __restrict__ feats, int* __restrict__ mode) {
    int i = blockIdx.x * 256 + threadIdx.x;
    if (i < na) a[i] = 0;
    if (i < nb) b[i] = 0.f;
    if (blockIdx.x == 0 && threadIdx.x == 0) {
        int sane = 0;
        for (int j = 0; j < 256; j++) {
            ushort u = feats[j];
            int e = (u >> 7) & 0xFF;
            if (u == 0 || (e >= 97 && e <= 157)) sane++;
        }
        *mode = (sane >= 220) ? 1 : 2;
    }
}

__global__ void k_deg_i(const int* __restrict__ dst, int* __restrict__ cnt) {
    int e = blockIdx.x * blockDim.x + threadIdx.x;
    if (e < N_EDGES) atomicAdd(&cnt[dst[e]], 1);
}
__global__ void k_scan(const int* __restrict__ cnt, int* __restrict__ indptr,
                       float* __restrict__ dinv) {
    __shared__ int part[256];
    int t = threadIdx.x;
    int base = t * 40;
    int s = 0;
    for (int i = 0; i < 40; i++) { int idx = base + i; if (idx < N_NODES) s += cnt[idx]; }
    part[t] = s;
    __syncthreads();
    if (t == 0) {
        int run = 0;
        for (int i = 0; i < 256; i++) { int tmp = part[i]; part[i] = run; run += tmp; }
        indptr[N_NODES] = run;
    }
    __syncthreads();
    int run = part[t];
    for (int i = 0; i < 40; i++) {
        int idx = base + i;
        if (idx < N_NODES) {
            indptr[idx] = run; run += cnt[idx];
            dinv[idx] = rsqrtf((float)cnt[idx] + 1.0f);  // +1 self loop
        }
    }
}
// fill + starts (merged)
__global__ void k_fill(const int* __restrict__ src, const int* __restrict__ dst,
                       const int* __restrict__ indptr, int* __restrict__ cursor,
                       const float* __restrict__ dinv, int* __restrict__ ecol,
                       float* __restrict__ ewgt, const int* __restrict__ batch,
                       int* __restrict__ starts) {
    int b = blockIdx.x;
    if (b < 313) {
        int e = b * 256 + threadIdx.x;
        if (e >= N_EDGES) return;
        int d = dst[e], s = src[e];
        int slot = indptr[d] + atomicAdd(&cursor[d], 1);
        ecol[slot] = s;
        ewgt[slot] = dinv[s] * dinv[d];
    } else {
        int i = (b - 313) * 256 + threadIdx.x;
        if (i > N_NODES) return;
        int bc = (i < N_NODES) ? batch[i] : NGRAPH;
        int bp = (i == 0) ? -1 : batch[i - 1];
        for (int g = bp + 1; g <= bc; g++) starts[g] = i;
    }
}

// ---------------- conversions (tiles + x0 + biases in one launch) -----------
__device__ __forceinline__ void cvt_tile(const void* W, int K, int N, int Kp,
                                         ushort* Wt, int n0, int k0, int md) {
    __shared__ float tile[32][33];
    int tx = threadIdx.x, ty = threadIdx.y;
    for (int r = ty; r < 32; r += 8) {
        int k = k0 + r;
        tile[r][tx] = (k < K) ? ldm(W, (long)k * N + n0 + tx, md) : 0.f;
    }
    __syncthreads();
    for (int r = ty; r < 32; r += 8) {
        int nn = n0 + r, kk = k0 + tx;
        if (kk < Kp) Wt[(long)nn * Kp + kk] = f2us(tile[tx][r]);
    }
}

__global__ void k_cvt_all(const void* W1, const void* W2, const void* W3,
                          const void* h1, const void* h2, const void* h3,
                          ushort* W1t, ushort* W2t, ushort* W3t,
                          ushort* h1t, ushort* h2t, ushort* h3t,
                          const int* __restrict__ types, const void* emb,
                          const void* feats, ushort* __restrict__ x0,
                          const void* b1, const void* b2, const void* b3,
                          float* __restrict__ b1f, float* __restrict__ b2f,
                          float* __restrict__ b3f, const int* __restrict__ mode) {
    int md = *mode;
    int b = blockIdx.x;
    if (b < 384) {
        int t = b;        cvt_tile(W1, IN_GNN, H1, IN_STRIDE, W1t, (t % 64) * 32, (t / 64) * 32, md);
    } else if (b < 2432) {
        int t = b - 384;  cvt_tile(W2, H1, H2, H1, W2t, (t % 32) * 32, (t / 32) * 32, md);
    } else if (b < 3456) {
        int t = b - 2432; cvt_tile(W3, H2, H2, H2, W3t, (t % 32) * 32, (t / 32) * 32, md);
    } else if (b < 4480) {
        int t = b - 3456; cvt_tile(h1, H2, H2, H2, h1t, (t % 32) * 32, (t / 32) * 32, md);
    } else if (b < 5504) {
        int t = b - 4480; cvt_tile(h2, H2, H2, H2, h2t, (t % 32) * 32, (t / 32) * 32, md);
    } else if (b < 6016) {
        int t = b - 5504; cvt_tile(h3, H2, 512, H2, h3t, (t % 16) * 32, (t / 16) * 32, md);
    } else if (b < 16016) {
        int i = b - 6016;                       // node index
        int c = threadIdx.y * 32 + threadIdx.x; // 0..255
        if (c >= IN_STRIDE) return;
        float v = 0.f;
        if (c < EMB_DIM) v = ldm(emb, (long)types[i] * EMB_DIM + c, md);
        else if (c < IN_GNN) v = ldm(feats, (long)i * FEAT_DIM + (c - EMB_DIM), md);
        x0[(long)i * IN_STRIDE + c] = f2us(v);
    } else {
        int i = (b - 16016) * 256 + threadIdx.y * 32 + threadIdx.x;
        if (i < 2048) b1f[i] = ldm(b1, i, md);
        else if (i < 3072) b2f[i - 2048] = ldm(b2, (long)(i - 2048), md);
        else if (i < 4096) b3f[i - 3072] = ldm(b3, (long)(i - 3072), md);
    }
}

__device__ __forceinline__ void unpack8(uint4 u, float* f) {
    f[0] = us2f((ushort)(u.x & 0xffff)); f[1] = us2f((ushort)(u.x >> 16));
    f[2] = us2f((ushort)(u.y & 0xffff)); f[3] = us2f((ushort)(u.y >> 16));
    f[4] = us2f((ushort)(u.z & 0xffff)); f[5] = us2f((ushort)(u.z >> 16));
    f[6] = us2f((ushort)(u.w & 0xffff)); f[7] = us2f((ushort)(u.w >> 16));
}

// ---------------- width-192 gather: edge-parallel uint4 ----------------
// 192 thr = 8 edge-groups x 24 col-chunks. Group eg covers edges s0+eg,
// s0+eg+8, ... each row read as 24 x uint4 (16B/lane, full 384B row/op).
// Partials reduced through 6KB LDS (epilogue only). Group 0 adds self term.
__global__ void k_gather192(const ushort* __restrict__ H, const int* __restrict__ indptr,
                            const int* __restrict__ ecol, const float* __restrict__ ewgt,
                            const float* __restrict__ dinv, ushort* __restrict__ X) {
    __shared__ float part[8][IN_STRIDE];
    int d = blockIdx.x;
    int tid = threadIdx.x;          // 0..191
    int cc = tid % 24, eg = tid / 24;
    int c8 = cc * 8;
    float a[8];
    if (eg == 0) {
        float w0 = dinv[d] * dinv[d];
        unpack8(*(const uint4*)&H[(long)d * IN_STRIDE + c8], a);
#pragma unroll
        for (int j = 0; j < 8; j++) a[j] *= w0;
    } else {
#pragma unroll
        for (int j = 0; j < 8; j++) a[j] = 0.f;
    }
    int s0 = indptr[d], s1 = indptr[d + 1];
    for (int s = s0 + eg; s < s1; s += 8) {
        int sc = ecol[s];
        float wv = ewgt[s];
        float f[8];
        unpack8(*(const uint4*)&H[(long)sc * IN_STRIDE + c8], f);
#pragma unroll
        for (int j = 0; j < 8; j++) a[j] += f[j] * wv;
    }
#pragma unroll
    for (int j = 0; j < 8; j++) part[eg][c8 + j] = a[j];
    __syncthreads();
    int c = tid;   // 0..191, one column each
    float s = part[0][c] + part[1][c] + part[2][c] + part[3][c]
            + part[4][c] + part[5][c] + part[6][c] + part[7][c];
    X[(long)d * IN_STRIDE + c] = f2us(s);
}

// width-1024 gather, XCD-sliced (r13): block L -> node L>>3, slice (L&7)*128.
__global__ __launch_bounds__(64) void k_gather_slice(
    const ushort* __restrict__ H, const int* __restrict__ indptr,
    const int* __restrict__ ecol, const float* __restrict__ ewgt,
    const float* __restrict__ dinv, const float* __restrict__ bias,
    ushort* __restrict__ X) {
    int L = blockIdx.x;
    int d = L >> 3;
    int c2 = (L & 7) * 128 + threadIdx.x * 2;   // 2 cols/lane, 4B loads
    float ds = dinv[d];
    float w0 = ds * ds;
    unsigned int u = *(const unsigned int*)&H[(long)d * H2 + c2];
    float a0 = us2f((ushort)(u & 0xffff)) * w0;
    float a1 = us2f((ushort)(u >> 16)) * w0;
    int s0 = indptr[d], s1 = indptr[d + 1];
    int s = s0;
    for (; s + 1 < s1; s += 2) {
        int sa = ecol[s], sb = ecol[s + 1];
        float wa = ewgt[s], wb = ewgt[s + 1];
        unsigned int ua = *(const unsigned int*)&H[(long)sa * H2 + c2];
        unsigned int ub = *(const unsigned int*)&H[(long)sb * H2 + c2];
        a0 += us2f((ushort)(ua & 0xffff)) * wa + us2f((ushort)(ub & 0xffff)) * wb;
        a1 += us2f((ushort)(ua >> 16)) * wa + us2f((ushort)(ub >> 16)) * wb;
    }
    if (s < s1) {
        unsigned int ua = *(const unsigned int*)&H[(long)ecol[s] * H2 + c2];
        float wa = ewgt[s];
        a0 += us2f((ushort)(ua & 0xffff)) * wa;
        a1 += us2f((ushort)(ua >> 16)) * wa;
    }
    unsigned int o = (unsigned int)f2us(fmaxf(a0 + bias[c2], 0.f))
                   | ((unsigned int)f2us(fmaxf(a1 + bias[c2 + 1], 0.f)) << 16);
    *(unsigned int*)&X[(long)d * H2 + c2] = o;
}

// ---------------- MFMA bf16 GEMM: round-10/12 proven config -----------------
__global__ __launch_bounds__(256) void k_mfma_gemm(
    const ushort* __restrict__ A, int lda, int M,
    const ushort* __restrict__ Wt, int K, int N,
    const float* __restrict__ bias, int relu,
    ushort* __restrict__ C, int NB) {
    __shared__ ushort As[2][128 * 32];
    __shared__ ushort Bs[2][128 * 32];
    int L = blockIdx.x;
    int i = L >> 3;
    int m_t = (L & 7) + (i / NB) * 8;
    int n_t = i % NB;
    int m0 = m_t * 128, n0 = n_t * 128;
    if (m0 >= M) return;
    int tid = threadIdx.x;
    int wave = tid >> 6, lane = tid & 63;
    int wm = (wave & 1) * 64, wn = (wave >> 1) * 64;
    int quad = lane >> 4, l16 = lane & 15;
    int srow = tid >> 2;
    int scol = (tid & 3) * 8;
    int swz = ((srow >> 1) & 3) << 3;
    int rwz = ((l16 >> 1) & 3) << 3;
    int wa0 = srow * 32 + (scol ^ swz);
    int wa1 = (64 + srow) * 32 + (scol ^ swz);

    f4v acc[4][4];
#pragma unroll
    for (int ii = 0; ii < 4; ii++)
#pragma unroll
        for (int jj = 0; jj < 4; jj++) acc[ii][jj] = (f4v)(0.f);

    int gm1 = m0 + srow;       if (gm1 >= M) gm1 = M - 1;
    int gm2 = m0 + 64 + srow;  if (gm2 >= M) gm2 = M - 1;
    const ushort* pa1 = A + (long)gm1 * lda + scol;
    const ushort* pa2 = A + (long)gm2 * lda + scol;
    const ushort* pb1 = Wt + (long)(n0 + srow) * K + scol;
    const ushort* pb2 = Wt + (long)(n0 + 64 + srow) * K + scol;

    int niter = K >> 5;
    s8b va1 = *(const s8b*)pa1;
    s8b va2 = *(const s8b*)pa2;
    s8b vb1 = *(const s8b*)pb1;
    s8b vb2 = *(const s8b*)pb2;
    *(s8b*)&As[0][wa0] = va1;
    *(s8b*)&As[0][wa1] = va2;
    *(s8b*)&Bs[0][wa0] = vb1;
    *(s8b*)&Bs[0][wa1] = vb2;
    if (niter > 1) {
        pa1 += 32; pa2 += 32; pb1 += 32; pb2 += 32;
        va1 = *(const s8b*)pa1;
        va2 = *(const s8b*)pa2;
        vb1 = *(const s8b*)pb1;
        vb2 = *(const s8b*)pb2;
    }

    for (int it = 0; it < niter; it++) {
        int cur = it & 1;
        __syncthreads();
        if (it + 1 < niter) {
            int nxt = cur ^ 1;
            *(s8b*)&As[nxt][wa0] = va1;
            *(s8b*)&As[nxt][wa1] = va2;
            *(s8b*)&Bs[nxt][wa0] = vb1;
            *(s8b*)&Bs[nxt][wa1] = vb2;
            if (it + 2 < niter) {
                pa1 += 32; pa2 += 32; pb1 += 32; pb2 += 32;
                va1 = *(const s8b*)pa1;
                va2 = *(const s8b*)pa2;
                vb1 = *(const s8b*)pb1;
                vb2 = *(const s8b*)pb2;
            }
        }
        s8b a[4], b[4];
#pragma unroll
        for (int ii = 0; ii < 4; ii++)
            a[ii] = *(const s8b*)&As[cur][(wm + ii * 16 + l16) * 32 + (quad * 8 ^ rwz)];
#pragma unroll
        for (int jj = 0; jj < 4; jj++)
            b[jj] = *(const s8b*)&Bs[cur][(wn + jj * 16 + l16) * 32 + (quad * 8 ^ rwz)];
#pragma unroll
        for (int ii = 0; ii < 4; ii++)
#pragma unroll
            for (int jj = 0; jj < 4; jj++)
                acc[ii][jj] = __builtin_amdgcn_mfma_f32_16x16x32_bf16(a[ii], b[jj], acc[ii][jj], 0, 0, 0);
    }

#pragma unroll
    for (int ii = 0; ii < 4; ii++) {
        int row0 = m0 + wm + ii * 16 + quad * 4;
#pragma unroll
        for (int jj = 0; jj < 4; jj++) {
            int colc = n0 + wn + jj * 16 + l16;
            float bv = bias ? bias[colc] : 0.f;
#pragma unroll
            for (int r = 0; r < 4; r++) {
                int row = row0 + r;
                if (row < M) {
                    float v = acc[ii][jj][r] + bv;
                    if (relu) v = fmaxf(v, 0.f);
                    C[(long)row * N + colc] = f2us(v);
                }
            }
        }
    }
}

// ---------------- pool stage 1 (PCHUNK=32: 2048 blocks) ----------------
__global__ void k_pool_part(const ushort* __restrict__ x, const int* __restrict__ starts,
                            float* __restrict__ acc) {
    int g = blockIdx.x / PCHUNK, ch = blockIdx.x % PCHUNK;
    int c = blockIdx.y * 256 + threadIdx.x;
    int s0 = starts[g], s1 = starts[g + 1];
    int len = s1 - s0;
    int per = (len + PCHUNK - 1) / PCHUNK;
    int r0 = s0 + ch * per;
    int r1 = r0 + per; if (r1 > s1) r1 = s1;
    if (r0 >= r1) return;
    float sum = 0.f;
    for (int i = r0; i < r1; i++) sum += us2f(x[(long)i * H2 + c]);
    atomicAdd(&acc[g * H2 + c], sum);
}

// ---------------- MLP head: full-K fused MFMA (reduce+bias+relu inline) -----
__global__ __launch_bounds__(256) void k_head_full(const ushort* __restrict__ A,
                                                   const ushort* __restrict__ Wt,
                                                   const void* __restrict__ bias,
                                                   ushort* __restrict__ out, int N,
                                                   const int* __restrict__ mode) {
    __shared__ float red[4][16][16];
    int md = *mode;
    int n0 = blockIdx.x * 16;
    int wave = threadIdx.x >> 6, lane = threadIdx.x & 63;
    int l16 = lane & 15, quad = lane >> 4;
    int kbase = wave * 256;
    f4v acc = (f4v)(0.f);
#pragma unroll
    for (int kk = 0; kk < 256; kk += 32) {
        int k = kbase + kk + quad * 8;
        s8b a = *(const s8b*)&A[l16 * 1024 + k];
        s8b b = *(const s8b*)&Wt[(long)(n0 + l16) * 1024 + k];
        acc = __builtin_amdgcn_mfma_f32_16x16x32_bf16(a, b, acc, 0, 0, 0);
    }
#pragma unroll
    for (int r = 0; r < 4; r++) red[wave][quad * 4 + r][l16] = acc[r];
    __syncthreads();
    int row = threadIdx.x >> 4, col = threadIdx.x & 15;
    float s = red[0][row][col] + red[1][row][col] + red[2][row][col] + red[3][row][col];
    s = fmaxf(s + ldm(bias, (long)(n0 + col), md), 0.f);
    out[(long)row * N + n0 + col] = f2us(s);
}

__global__ __launch_bounds__(256) void k_head_full_pool(const float* __restrict__ pacc,
                                                        const int* __restrict__ starts,
                                                        const ushort* __restrict__ Wt,
                                                        const void* __restrict__ bias,
                                                        ushort* __restrict__ out, int N,
                                                        const int* __restrict__ mode) {
    __shared__ float red[4][16][16];
    int md = *mode;
    int n0 = blockIdx.x * 16;
    int wave = threadIdx.x >> 6, lane = threadIdx.x & 63;
    int l16 = lane & 15, quad = lane >> 4;
    int cnt = starts[l16 + 1] - starts[l16];
    float rc = 1.f / (float)(cnt > 0 ? cnt : 1);
    int kbase = wave * 256;
    f4v acc = (f4v)(0.f);
#pragma unroll
    for (int kk = 0; kk < 256; kk += 32) {
        int k = kbase + kk + quad * 8;
        s8b a;
        short* ap = (short*)&a;
#pragma unroll
        for (int j = 0; j < 8; j++) ap[j] = (short)f2us(pacc[l16 * 1024 + k + j] * rc);
        s8b b = *(const s8b*)&Wt[(long)(n0 + l16) * 1024 + k];
        acc = __builtin_amdgcn_mfma_f32_16x16x32_bf16(a, b, acc, 0, 0, 0);
    }
#pragma unroll
    for (int r = 0; r < 4; r++) red[wave][quad * 4 + r][l16] = acc[r];
    __syncthreads();
    int row = threadIdx.x >> 4, col = threadIdx.x & 15;
    float s = red[0][row][col] + red[1][row][col] + red[2][row][col] + red[3][row][col];
    s = fmaxf(s + ldm(bias, (long)(n0 + col), md), 0.f);
    out[(long)row * N + n0 + col] = f2us(s);
}

__global__ void k_head_out(const ushort* __restrict__ in, const void* __restrict__ W,
                           const void* __restrict__ b, void* __restrict__ out,
                           const int* __restrict__ mode) {
    int md = *mode;
    int row = blockIdx.x >> 1, cls = blockIdx.x & 1;
    int lane = threadIdx.x;
    float acc = 0.f;
    for (int k = lane; k < 512; k += 64)
        acc += us2f(in[row * 512 + k]) * ldm(W, (long)k * NCLS + cls, md);
#pragma unroll
    for (int off = 32; off > 0; off >>= 1) acc += __shfl_down(acc, off);
    if (lane == 0) {
        float v = acc + ldm(b, (long)cls, md);
        if (md == 1) ((ushort*)out)[row * NCLS + cls] = f2us(v);
        else ((float*)out)[row * NCLS + cls] = v;
    }
}

extern "C" void kernel_launch(void* const* d_in, const int* in_sizes, int n_in,
                              void* d_out, int out_size, void* d_ws, size_t ws_size,
                              hipStream_t stream) {
    static const int EXPECT[19] = {
        10000, 630000, 160000, 10000, 128000,
        391168, 2048, 2097152, 1024, 1048576, 1024,
        1048576, 1024, 1048576, 1024, 524288, 512, 1024, 2
    };
    if (n_in != 19) { hipMemsetAsync(d_out, 0x48, 64, stream); return; }
    for (int i = 0; i < 19; i++)
        if (in_sizes[i] != EXPECT[i]) { hipMemsetAsync(d_out, 0x50 + i, 64, stream); return; }
    if (ws_size < (size_t)90000000) { hipMemsetAsync(d_out, 0x49, 64, stream); return; }

    const int* node_types = (const int*)d_in[0];
    const void* other = d_in[1];
    const int* e_src = (const int*)d_in[2];
    const int* e_dst = e_src + N_EDGES;
    const int* batch = (const int*)d_in[3];

    // --- workspace carve-up (~83 MB) ---
    char* w = (char*)d_ws;
    int* mode = (int*)w;      w += 256;
    int* cnt = (int*)w;       w += 10240 * 4;
    int* cursor = (int*)w;    w += 10240 * 4;
    float* dinv = (float*)w;  w += 10240 * 4;
    int* starts = (int*)w;    w += 256;
    int* indptr = (int*)w;    w += 10240 * 4;
    int* ecol = (int*)w;      w += 81920 * 4;
    float* ewgt = (float*)w;  w += 81920 * 4;
    float* b1f = (float*)w;   w += 2048 * 4;
    float* b2f = (float*)w;   w += 1024 * 4;
    float* b3f = (float*)w;   w += 1024 * 4;
    float* pacc = (float*)w;  w += 16 * 1024 * 4;       // pool fp32 accumulator
    ushort* hA = (ushort*)w;  w += 16 * 1024 * 2;
    ushort* hB = (ushort*)w;  w += 16 * 1024 * 2;
    ushort* x0 = (ushort*)w;  w += 1920000 * 2;         // N x 192
    ushort* A1 = (ushort*)w;  w += 1920000 * 2;         // N x 192 aggregated
    ushort* W1t = (ushort*)w; w += 393216 * 2;          // 2048 x 192
    ushort* W2t = (ushort*)w; w += 2097152 * 2;         // 1024 x 2048
    ushort* W3t = (ushort*)w; w += 1048576 * 2;         // 1024 x 1024
    ushort* h1wt = (ushort*)w; w += 1048576 * 2;        // 1024 x 1024
    ushort* h2wt = (ushort*)w; w += 1048576 * 2;        // 1024 x 1024
    ushort* h3wt = (ushort*)w; w += 524288 * 2;         // 512 x 1024
    ushort* Hb = (ushort*)w;  w += 20480000 * 2;        // N x 2048 (x1; later x2|x3)
    ushort* Gb = (ushort*)w;  w += 10240000 * 2;        // N x 1024 (gemm2/3 out)
    ushort* x2 = Hb;
    ushort* x3 = Hb + (size_t)N_NODES * H2;

    hipGetLastError();
    k_prep0<<<80, 256, 0, stream>>>(cnt, 20480, pacc, NGRAPH * H2, (const ushort*)other, mode);
    hipError_t e0 = hipGetLastError();
    if (e0 != hipSuccess) { hipMemsetAsync(d_out, 0x46, 64, stream); return; }
    k_deg_i<<<(N_EDGES + 255) / 256, 256, 0, stream>>>(e_dst, cnt);
    k_scan<<<1, 256, 0, stream>>>(cnt, indptr, dinv);
    k_fill<<<313 + 40, 256, 0, stream>>>(e_src, e_dst, indptr, cursor, dinv, ecol, ewgt, batch, starts);

    // conversions: weight tiles + x0 + biases in one launch
    k_cvt_all<<<16032, dim3(32, 8), 0, stream>>>(d_in[5], d_in[7], d_in[9], d_in[11], d_in[13], d_in[15],
                                                 W1t, W2t, W3t, h1wt, h2wt, h3wt,
                                                 node_types, d_in[4], other, x0,
                                                 d_in[6], d_in[8], d_in[10], b1f, b2f, b3f, mode);

    // layer 1: aggregate x0 (width 192, edge-parallel) then GEMM 192->2048
    k_gather192<<<N_NODES, IN_STRIDE, 0, stream>>>(x0, indptr, ecol, ewgt, dinv, A1);
    k_mfma_gemm<<<16 * 80, 256, 0, stream>>>(A1, IN_STRIDE, N_NODES, W1t, IN_STRIDE, H1, b1f, 1, Hb, 16);

    // layer 2: GEMM 2048->1024, then XCD-sliced gather + bias + relu
    k_mfma_gemm<<<8 * 80, 256, 0, stream>>>(Hb, H1, N_NODES, W2t, H1, H2, nullptr, 0, Gb, 8);
    k_gather_slice<<<N_NODES * 8, 64, 0, stream>>>(Gb, indptr, ecol, ewgt, dinv, b2f, x2);

    // layer 3: GEMM 1024->1024, then XCD-sliced gather + bias + relu
    k_mfma_gemm<<<8 * 80, 256, 0, stream>>>(x2, H2, N_NODES, W3t, H2, H2, nullptr, 0, Gb, 8);
    k_gather_slice<<<N_NODES * 8, 64, 0, stream>>>(Gb, indptr, ecol, ewgt, dinv, b3f, x3);

    // pool partials; mean-normalize fused into head layer 1
    k_pool_part<<<dim3(NGRAPH * PCHUNK, H2 / 256), 256, 0, stream>>>(x3, starts, pacc);

    // MLP head: full-K fused per layer
    k_head_full_pool<<<64, 256, 0, stream>>>(pacc, starts, h1wt, d_in[12], hA, 1024, mode);
    k_head_full<<<64, 256, 0, stream>>>(hA, h2wt, d_in[14], hB, 1024, mode);
    k_head_full<<<32, 256, 0, stream>>>(hB, h3wt, d_in[16], hA, 512, mode);
    k_head_out<<<NGRAPH * NCLS, 64, 0, stream>>>(hA, d_in[17], d_in[18], d_out, mode);

    hipError_t e1 = hipGetLastError();
    if (e1 != hipSuccess) hipMemsetAsync(d_out, 0x47, 64, stream);
}

// Round 17
// 384.433 us; speedup vs baseline: 1.1956x; 1.0053x over previous
//
#include <hip/hip_runtime.h>

// GraphV1EmbLarge round 17: dispatch-count reduction on the r16 best (386.5us).
//  - k_prep0 -> 2x hipMemsetAsync (cnt+cursor adjacent: one memset) + dtype
//    detect folded into k_deg_i.
//  - k_fill/k_starts folded into k_cvt_all (both only need scan's indptr).
//  16 kernels -> 12 kernels + 2 memsets (~3 graph-replay gaps removed).
// All compute kernels byte-identical to r16. Established plateaus: gemm2
// ~70us (5 attacks), gathers, head, pool. If this round is neutral, the
// decomposition is at its structural floor.

#define N_NODES 10000
#define N_EDGES 80000
#define EMB_DIM 128
#define FEAT_DIM 63
#define IN_GNN 191
#define IN_STRIDE 192
#define H1 2048
#define H2 1024
#define NGRAPH 16
#define NCLS 2
#define PCHUNK 32

using ushort = unsigned short;
typedef __attribute__((ext_vector_type(8))) short s8b;   // 8 bf16 (4 VGPRs)
typedef __attribute__((ext_vector_type(4))) float f4v;   // 4 fp32 acc

__device__ __forceinline__ float us2f(ushort u) {
    union { unsigned int i; float f; } v; v.i = ((unsigned int)u) << 16; return v.f;
}
__device__ __forceinline__ ushort f2us(float f) {
    union { unsigned int i; float f; } v; v.f = f;
    unsigned int r = v.i + 0x7FFFu + ((v.i >> 16) & 1u);
    return (ushort)(r >> 16);
}
__device__ __forceinline__ float ldm(const void* p, long i, int md) {
    return (md == 1) ? us2f(((const ushort*)p)[i]) : ((const float*)p)[i];
}

__global__ void GraphV1EmbLarge_73864847556672_kernel() {}

// ---------------- degree count + dtype detect (merged) ----------------
__global__ void k_deg_i(const int* __restrict__ dst, int* __restrict__ cnt,
                        const ushort* __restrict__ feats, int* __restrict__ mode) {
    int e = blockIdx.x * blockDim.x + threadIdx.x;
    if (e < N_EDGES) atomicAdd(&cnt[dst[e]], 1);
    if (blockIdx.x == 0 && threadIdx.x == 0) {
        int sane = 0;
        for (int j = 0; j < 256; j++) {
            ushort u = feats[j];
            int ex = (u >> 7) & 0xFF;
            if (u == 0 || (ex >= 97 && ex <= 157)) sane++;
        }
        *mode = (sane >= 220) ? 1 : 2;
    }
}

__global__ void k_scan(const int* __restrict__ cnt, int* __restrict__ indptr,
                       float* __restrict__ dinv) {
    __shared__ int part[256];
    int t = threadIdx.x;
    int base = t * 40;
    int s = 0;
    for (int i = 0; i < 40; i++) { int idx = base + i; if (idx < N_NODES) s += cnt[idx]; }
    part[t] = s;
    __syncthreads();
    if (t == 0) {
        int run = 0;
        for (int i = 0; i < 256; i++) { int tmp = part[i]; part[i] = run; run += tmp; }
        indptr[N_NODES] = run;
    }
    __syncthreads();
    int run = part[t];
    for (int i = 0; i < 40; i++) {
        int idx = base + i;
        if (idx < N_NODES) {
            indptr[idx] = run; run += cnt[idx];
            dinv[idx] = rsqrtf((float)cnt[idx] + 1.0f);  // +1 self loop
        }
    }
}

// ---------------- conversions + CSR fill + starts (one launch) ----------------
__device__ __forceinline__ void cvt_tile(const void* W, int K, int N, int Kp,
                                         ushort* Wt, int n0, int k0, int md) {
    __shared__ float tile[32][33];
    int tx = threadIdx.x, ty = threadIdx.y;
    for (int r = ty; r < 32; r += 8) {
        int k = k0 + r;
        tile[r][tx] = (k < K) ? ldm(W, (long)k * N + n0 + tx, md) : 0.f;
    }
    __syncthreads();
    for (int r = ty; r < 32; r += 8) {
        int nn = n0 + r, kk = k0 + tx;
        if (kk < Kp) Wt[(long)nn * Kp + kk] = f2us(tile[tx][r]);
    }
}

// [0,384) W1 | [384,2432) W2 | [2432,3456) W3 | [3456,4480) h1 | [4480,5504) h2
// [5504,6016) h3 | [6016,16016) x0 | [16016,16032) biases
// [16032,16345) edge fill | [16345,16385) starts
__global__ void k_cvt_all(const void* W1, const void* W2, const void* W3,
                          const void* h1, const void* h2, const void* h3,
                          ushort* W1t, ushort* W2t, ushort* W3t,
                          ushort* h1t, ushort* h2t, ushort* h3t,
                          const int* __restrict__ types, const void* emb,
                          const void* feats, ushort* __restrict__ x0,
                          const void* b1, const void* b2, const void* b3,
                          float* __restrict__ b1f, float* __restrict__ b2f,
                          float* __restrict__ b3f, const int* __restrict__ mode,
                          const int* __restrict__ e_src, const int* __restrict__ e_dst,
                          const int* __restrict__ indptr, int* __restrict__ cursor,
                          const float* __restrict__ dinv, int* __restrict__ ecol,
                          float* __restrict__ ewgt, const int* __restrict__ batch,
                          int* __restrict__ starts) {
    int md = *mode;
    int b = blockIdx.x;
    if (b < 384) {
        int t = b;        cvt_tile(W1, IN_GNN, H1, IN_STRIDE, W1t, (t % 64) * 32, (t / 64) * 32, md);
    } else if (b < 2432) {
        int t = b - 384;  cvt_tile(W2, H1, H2, H1, W2t, (t % 32) * 32, (t / 32) * 32, md);
    } else if (b < 3456) {
        int t = b - 2432; cvt_tile(W3, H2, H2, H2, W3t, (t % 32) * 32, (t / 32) * 32, md);
    } else if (b < 4480) {
        int t = b - 3456; cvt_tile(h1, H2, H2, H2, h1t, (t % 32) * 32, (t / 32) * 32, md);
    } else if (b < 5504) {
        int t = b - 4480; cvt_tile(h2, H2, H2, H2, h2t, (t % 32) * 32, (t / 32) * 32, md);
    } else if (b < 6016) {
        int t = b - 5504; cvt_tile(h3, H2, 512, H2, h3t, (t % 16) * 32, (t / 16) * 32, md);
    } else if (b < 16016) {
        int i = b - 6016;                       // node index
        int c = threadIdx.y * 32 + threadIdx.x; // 0..255
        if (c >= IN_STRIDE) return;
        float v = 0.f;
        if (c < EMB_DIM) v = ldm(emb, (long)types[i] * EMB_DIM + c, md);
        else if (c < IN_GNN) v = ldm(feats, (long)i * FEAT_DIM + (c - EMB_DIM), md);
        x0[(long)i * IN_STRIDE + c] = f2us(v);
    } else if (b < 16032) {
        int i = (b - 16016) * 256 + threadIdx.y * 32 + threadIdx.x;
        if (i < 2048) b1f[i] = ldm(b1, i, md);
        else if (i < 3072) b2f[i - 2048] = ldm(b2, (long)(i - 2048), md);
        else if (i < 4096) b3f[i - 3072] = ldm(b3, (long)(i - 3072), md);
    } else if (b < 16345) {
        int e = (b - 16032) * 256 + threadIdx.y * 32 + threadIdx.x;
        if (e >= N_EDGES) return;
        int d = e_dst[e], s = e_src[e];
        int slot = indptr[d] + atomicAdd(&cursor[d], 1);
        ecol[slot] = s;
        ewgt[slot] = dinv[s] * dinv[d];
    } else {
        int i = (b - 16345) * 256 + threadIdx.y * 32 + threadIdx.x;
        if (i > N_NODES) return;
        int bc = (i < N_NODES) ? batch[i] : NGRAPH;
        int bp = (i == 0) ? -1 : batch[i - 1];
        for (int g = bp + 1; g <= bc; g++) starts[g] = i;
    }
}

__device__ __forceinline__ void unpack8(uint4 u, float* f) {
    f[0] = us2f((ushort)(u.x & 0xffff)); f[1] = us2f((ushort)(u.x >> 16));
    f[2] = us2f((ushort)(u.y & 0xffff)); f[3] = us2f((ushort)(u.y >> 16));
    f[4] = us2f((ushort)(u.z & 0xffff)); f[5] = us2f((ushort)(u.z >> 16));
    f[6] = us2f((ushort)(u.w & 0xffff)); f[7] = us2f((ushort)(u.w >> 16));
}

// ---------------- width-192 gather: edge-parallel uint4 (r16) ----------------
__global__ void k_gather192(const ushort* __restrict__ H, const int* __restrict__ indptr,
                            const int* __restrict__ ecol, const float* __restrict__ ewgt,
                            const float* __restrict__ dinv, ushort* __restrict__ X) {
    __shared__ float part[8][IN_STRIDE];
    int d = blockIdx.x;
    int tid = threadIdx.x;          // 0..191
    int cc = tid % 24, eg = tid / 24;
    int c8 = cc * 8;
    float a[8];
    if (eg == 0) {
        float w0 = dinv[d] * dinv[d];
        unpack8(*(const uint4*)&H[(long)d * IN_STRIDE + c8], a);
#pragma unroll
        for (int j = 0; j < 8; j++) a[j] *= w0;
    } else {
#pragma unroll
        for (int j = 0; j < 8; j++) a[j] = 0.f;
    }
    int s0 = indptr[d], s1 = indptr[d + 1];
    for (int s = s0 + eg; s < s1; s += 8) {
        int sc = ecol[s];
        float wv = ewgt[s];
        float f[8];
        unpack8(*(const uint4*)&H[(long)sc * IN_STRIDE + c8], f);
#pragma unroll
        for (int j = 0; j < 8; j++) a[j] += f[j] * wv;
    }
#pragma unroll
    for (int j = 0; j < 8; j++) part[eg][c8 + j] = a[j];
    __syncthreads();
    int c = tid;
    float s = part[0][c] + part[1][c] + part[2][c] + part[3][c]
            + part[4][c] + part[5][c] + part[6][c] + part[7][c];
    X[(long)d * IN_STRIDE + c] = f2us(s);
}

// width-1024 gather, XCD-sliced (r13)
__global__ __launch_bounds__(64) void k_gather_slice(
    const ushort* __restrict__ H, const int* __restrict__ indptr,
    const int* __restrict__ ecol, const float* __restrict__ ewgt,
    const float* __restrict__ dinv, const float* __restrict__ bias,
    ushort* __restrict__ X) {
    int L = blockIdx.x;
    int d = L >> 3;
    int c2 = (L & 7) * 128 + threadIdx.x * 2;
    float ds = dinv[d];
    float w0 = ds * ds;
    unsigned int u = *(const unsigned int*)&H[(long)d * H2 + c2];
    float a0 = us2f((ushort)(u & 0xffff)) * w0;
    float a1 = us2f((ushort)(u >> 16)) * w0;
    int s0 = indptr[d], s1 = indptr[d + 1];
    int s = s0;
    for (; s + 1 < s1; s += 2) {
        int sa = ecol[s], sb = ecol[s + 1];
        float wa = ewgt[s], wb = ewgt[s + 1];
        unsigned int ua = *(const unsigned int*)&H[(long)sa * H2 + c2];
        unsigned int ub = *(const unsigned int*)&H[(long)sb * H2 + c2];
        a0 += us2f((ushort)(ua & 0xffff)) * wa + us2f((ushort)(ub & 0xffff)) * wb;
        a1 += us2f((ushort)(ua >> 16)) * wa + us2f((ushort)(ub >> 16)) * wb;
    }
    if (s < s1) {
        unsigned int ua = *(const unsigned int*)&H[(long)ecol[s] * H2 + c2];
        float wa = ewgt[s];
        a0 += us2f((ushort)(ua & 0xffff)) * wa;
        a1 += us2f((ushort)(ua >> 16)) * wa;
    }
    unsigned int o = (unsigned int)f2us(fmaxf(a0 + bias[c2], 0.f))
                   | ((unsigned int)f2us(fmaxf(a1 + bias[c2 + 1], 0.f)) << 16);
    *(unsigned int*)&X[(long)d * H2 + c2] = o;
}

// ---------------- MFMA bf16 GEMM: round-10/12 proven config -----------------
__global__ __launch_bounds__(256) void k_mfma_gemm(
    const ushort* __restrict__ A, int lda, int M,
    const ushort* __restrict__ Wt, int K, int N,
    const float* __restrict__ bias, int relu,
    ushort* __restrict__ C, int NB) {
    __shared__ ushort As[2][128 * 32];
    __shared__ ushort Bs[2][128 * 32];
    int L = blockIdx.x;
    int i = L >> 3;
    int m_t = (L & 7) + (i / NB) * 8;
    int n_t = i % NB;
    int m0 = m_t * 128, n0 = n_t * 128;
    if (m0 >= M) return;
    int tid = threadIdx.x;
    int wave = tid >> 6, lane = tid & 63;
    int wm = (wave & 1) * 64, wn = (wave >> 1) * 64;
    int quad = lane >> 4, l16 = lane & 15;
    int srow = tid >> 2;
    int scol = (tid & 3) * 8;
    int swz = ((srow >> 1) & 3) << 3;
    int rwz = ((l16 >> 1) & 3) << 3;
    int wa0 = srow * 32 + (scol ^ swz);
    int wa1 = (64 + srow) * 32 + (scol ^ swz);

    f4v acc[4][4];
#pragma unroll
    for (int ii = 0; ii < 4; ii++)
#pragma unroll
        for (int jj = 0; jj < 4; jj++) acc[ii][jj] = (f4v)(0.f);

    int gm1 = m0 + srow;       if (gm1 >= M) gm1 = M - 1;
    int gm2 = m0 + 64 + srow;  if (gm2 >= M) gm2 = M - 1;
    const ushort* pa1 = A + (long)gm1 * lda + scol;
    const ushort* pa2 = A + (long)gm2 * lda + scol;
    const ushort* pb1 = Wt + (long)(n0 + srow) * K + scol;
    const ushort* pb2 = Wt + (long)(n0 + 64 + srow) * K + scol;

    int niter = K >> 5;
    s8b va1 = *(const s8b*)pa1;
    s8b va2 = *(const s8b*)pa2;
    s8b vb1 = *(const s8b*)pb1;
    s8b vb2 = *(const s8b*)pb2;
    *(s8b*)&As[0][wa0] = va1;
    *(s8b*)&As[0][wa1] = va2;
    *(s8b*)&Bs[0][wa0] = vb1;
    *(s8b*)&Bs[0][wa1] = vb2;
    if (niter > 1) {
        pa1 += 32; pa2 += 32; pb1 += 32; pb2 += 32;
        va1 = *(const s8b*)pa1;
        va2 = *(const s8b*)pa2;
        vb1 = *(const s8b*)pb1;
        vb2 = *(const s8b*)pb2;
    }

    for (int it = 0; it < niter; it++) {
        int cur = it & 1;
        __syncthreads();
        if (it + 1 < niter) {
            int nxt = cur ^ 1;
            *(s8b*)&As[nxt][wa0] = va1;
            *(s8b*)&As[nxt][wa1] = va2;
            *(s8b*)&Bs[nxt][wa0] = vb1;
            *(s8b*)&Bs[nxt][wa1] = vb2;
            if (it + 2 < niter) {
                pa1 += 32; pa2 += 32; pb1 += 32; pb2 += 32;
                va1 = *(const s8b*)pa1;
                va2 = *(const s8b*)pa2;
                vb1 = *(const s8b*)pb1;
                vb2 = *(const s8b*)pb2;
            }
        }
        s8b a[4], b[4];
#pragma unroll
        for (int ii = 0; ii < 4; ii++)
            a[ii] = *(const s8b*)&As[cur][(wm + ii * 16 + l16) * 32 + (quad * 8 ^ rwz)];
#pragma unroll
        for (int jj = 0; jj < 4; jj++)
            b[jj] = *(const s8b*)&Bs[cur][(wn + jj * 16 + l16) * 32 + (quad * 8 ^ rwz)];
#pragma unroll
        for (int ii = 0; ii < 4; ii++)
#pragma unroll
            for (int jj = 0; jj < 4; jj++)
                acc[ii][jj] = __builtin_amdgcn_mfma_f32_16x16x32_bf16(a[ii], b[jj], acc[ii][jj], 0, 0, 0);
    }

#pragma unroll
    for (int ii = 0; ii < 4; ii++) {
        int row0 = m0 + wm + ii * 16 + quad * 4;
#pragma unroll
        for (int jj = 0; jj < 4; jj++) {
            int colc = n0 + wn + jj * 16 + l16;
            float bv = bias ? bias[colc] : 0.f;
#pragma unroll
            for (int r = 0; r < 4; r++) {
                int row = row0 + r;
                if (row < M) {
                    float v = acc[ii][jj][r] + bv;
                    if (relu) v = fmaxf(v, 0.f);
                    C[(long)row * N + colc] = f2us(v);
                }
            }
        }
    }
}

// ---------------- pool stage 1 (PCHUNK=32: 2048 blocks) ----------------
__global__ void k_pool_part(const ushort* __restrict__ x, const int* __restrict__ starts,
                            float* __restrict__ acc) {
    int g = blockIdx.x / PCHUNK, ch = blockIdx.x % PCHUNK;
    int c = blockIdx.y * 256 + threadIdx.x;
    int s0 = starts[g], s1 = starts[g + 1];
    int len = s1 - s0;
    int per = (len + PCHUNK - 1) / PCHUNK;
    int r0 = s0 + ch * per;
    int r1 = r0 + per; if (r1 > s1) r1 = s1;
    if (r0 >= r1) return;
    float sum = 0.f;
    for (int i = r0; i < r1; i++) sum += us2f(x[(long)i * H2 + c]);
    atomicAdd(&acc[g * H2 + c], sum);
}

// ---------------- MLP head: full-K fused MFMA (reduce+bias+relu inline) -----
__global__ __launch_bounds__(256) void k_head_full(const ushort* __restrict__ A,
                                                   const ushort* __restrict__ Wt,
                                                   const void* __restrict__ bias,
                                                   ushort* __restrict__ out, int N,
                                                   const int* __restrict__ mode) {
    __shared__ float red[4][16][16];
    int md = *mode;
    int n0 = blockIdx.x * 16;
    int wave = threadIdx.x >> 6, lane = threadIdx.x & 63;
    int l16 = lane & 15, quad = lane >> 4;
    int kbase = wave * 256;
    f4v acc = (f4v)(0.f);
#pragma unroll
    for (int kk = 0; kk < 256; kk += 32) {
        int k = kbase + kk + quad * 8;
        s8b a = *(const s8b*)&A[l16 * 1024 + k];
        s8b b = *(const s8b*)&Wt[(long)(n0 + l16) * 1024 + k];
        acc = __builtin_amdgcn_mfma_f32_16x16x32_bf16(a, b, acc, 0, 0, 0);
    }
#pragma unroll
    for (int r = 0; r < 4; r++) red[wave][quad * 4 + r][l16] = acc[r];
    __syncthreads();
    int row = threadIdx.x >> 4, col = threadIdx.x & 15;
    float s = red[0][row][col] + red[1][row][col] + red[2][row][col] + red[3][row][col];
    s = fmaxf(s + ldm(bias, (long)(n0 + col), md), 0.f);
    out[(long)row * N + n0 + col] = f2us(s);
}

__global__ __launch_bounds__(256) void k_head_full_pool(const float* __restrict__ pacc,
                                                        const int* __restrict__ starts,
                                                        const ushort* __restrict__ Wt,
                                                        const void* __restrict__ bias,
                                                        ushort* __restrict__ out, int N,
                                                        const int* __restrict__ mode) {
    __shared__ float red[4][16][16];
    int md = *mode;
    int n0 = blockIdx.x * 16;
    int wave = threadIdx.x >> 6, lane = threadIdx.x & 63;
    int l16 = lane & 15, quad = lane >> 4;
    int cnt = starts[l16 + 1] - starts[l16];
    float rc = 1.f / (float)(cnt > 0 ? cnt : 1);
    int kbase = wave * 256;
    f4v acc = (f4v)(0.f);
#pragma unroll
    for (int kk = 0; kk < 256; kk += 32) {
        int k = kbase + kk + quad * 8;
        s8b a;
        short* ap = (short*)&a;
#pragma unroll
        for (int j = 0; j < 8; j++) ap[j] = (short)f2us(pacc[l16 * 1024 + k + j] * rc);
        s8b b = *(const s8b*)&Wt[(long)(n0 + l16) * 1024 + k];
        acc = __builtin_amdgcn_mfma_f32_16x16x32_bf16(a, b, acc, 0, 0, 0);
    }
#pragma unroll
    for (int r = 0; r < 4; r++) red[wave][quad * 4 + r][l16] = acc[r];
    __syncthreads();
    int row = threadIdx.x >> 4, col = threadIdx.x & 15;
    float s = red[0][row][col] + red[1][row][col] + red[2][row][col] + red[3][row][col];
    s = fmaxf(s + ldm(bias, (long)(n0 + col), md), 0.f);
    out[(long)row * N + n0 + col] = f2us(s);
}

__global__ void k_head_out(const ushort* __restrict__ in, const void* __restrict__ W,
                           const void* __restrict__ b, void* __restrict__ out,
                           const int* __restrict__ mode) {
    int md = *mode;
    int row = blockIdx.x >> 1, cls = blockIdx.x & 1;
    int lane = threadIdx.x;
    float acc = 0.f;
    for (int k = lane; k < 512; k += 64)
        acc += us2f(in[row * 512 + k]) * ldm(W, (long)k * NCLS + cls, md);
#pragma unroll
    for (int off = 32; off > 0; off >>= 1) acc += __shfl_down(acc, off);
    if (lane == 0) {
        float v = acc + ldm(b, (long)cls, md);
        if (md == 1) ((ushort*)out)[row * NCLS + cls] = f2us(v);
        else ((float*)out)[row * NCLS + cls] = v;
    }
}

extern "C" void kernel_launch(void* const* d_in, const int* in_sizes, int n_in,
                              void* d_out, int out_size, void* d_ws, size_t ws_size,
                              hipStream_t stream) {
    static const int EXPECT[19] = {
        10000, 630000, 160000, 10000, 128000,
        391168, 2048, 2097152, 1024, 1048576, 1024,
        1048576, 1024, 1048576, 1024, 524288, 512, 1024, 2
    };
    if (n_in != 19) { hipMemsetAsync(d_out, 0x48, 64, stream); return; }
    for (int i = 0; i < 19; i++)
        if (in_sizes[i] != EXPECT[i]) { hipMemsetAsync(d_out, 0x50 + i, 64, stream); return; }
    if (ws_size < (size_t)90000000) { hipMemsetAsync(d_out, 0x49, 64, stream); return; }

    const int* node_types = (const int*)d_in[0];
    const void* other = d_in[1];
    const int* e_src = (const int*)d_in[2];
    const int* e_dst = e_src + N_EDGES;
    const int* batch = (const int*)d_in[3];

    // --- workspace carve-up (~83 MB) ---
    char* w = (char*)d_ws;
    int* mode = (int*)w;      w += 256;
    int* cnt = (int*)w;       w += 10240 * 4;
    int* cursor = (int*)w;    w += 10240 * 4;
    float* dinv = (float*)w;  w += 10240 * 4;
    int* starts = (int*)w;    w += 256;
    int* indptr = (int*)w;    w += 10240 * 4;
    int* ecol = (int*)w;      w += 81920 * 4;
    float* ewgt = (float*)w;  w += 81920 * 4;
    float* b1f = (float*)w;   w += 2048 * 4;
    float* b2f = (float*)w;   w += 1024 * 4;
    float* b3f = (float*)w;   w += 1024 * 4;
    float* pacc = (float*)w;  w += 16 * 1024 * 4;       // pool fp32 accumulator
    ushort* hA = (ushort*)w;  w += 16 * 1024 * 2;
    ushort* hB = (ushort*)w;  w += 16 * 1024 * 2;
    ushort* x0 = (ushort*)w;  w += 1920000 * 2;         // N x 192
    ushort* A1 = (ushort*)w;  w += 1920000 * 2;         // N x 192 aggregated
    ushort* W1t = (ushort*)w; w += 393216 * 2;          // 2048 x 192
    ushort* W2t = (ushort*)w; w += 2097152 * 2;         // 1024 x 2048
    ushort* W3t = (ushort*)w; w += 1048576 * 2;         // 1024 x 1024
    ushort* h1wt = (ushort*)w; w += 1048576 * 2;        // 1024 x 1024
    ushort* h2wt = (ushort*)w; w += 1048576 * 2;        // 1024 x 1024
    ushort* h3wt = (ushort*)w; w += 524288 * 2;         // 512 x 1024
    ushort* Hb = (ushort*)w;  w += 20480000 * 2;        // N x 2048 (x1; later x2|x3)
    ushort* Gb = (ushort*)w;  w += 10240000 * 2;        // N x 1024 (gemm2/3 out)
    ushort* x2 = Hb;
    ushort* x3 = Hb + (size_t)N_NODES * H2;

    hipGetLastError();
    // zeroing via DMA memsets (cnt+cursor adjacent -> one call), pacc second
    hipMemsetAsync(cnt, 0, 20480 * 4, stream);
    hipMemsetAsync(pacc, 0, NGRAPH * H2 * 4, stream);
    k_deg_i<<<(N_EDGES + 255) / 256, 256, 0, stream>>>(e_dst, cnt, (const ushort*)other, mode);
    hipError_t e0 = hipGetLastError();
    if (e0 != hipSuccess) { hipMemsetAsync(d_out, 0x46, 64, stream); return; }
    k_scan<<<1, 256, 0, stream>>>(cnt, indptr, dinv);

    // conversions + CSR fill + starts in one launch
    k_cvt_all<<<16385, dim3(32, 8), 0, stream>>>(d_in[5], d_in[7], d_in[9], d_in[11], d_in[13], d_in[15],
                                                 W1t, W2t, W3t, h1wt, h2wt, h3wt,
                                                 node_types, d_in[4], other, x0,
                                                 d_in[6], d_in[8], d_in[10], b1f, b2f, b3f, mode,
                                                 e_src, e_dst, indptr, cursor, dinv, ecol, ewgt,
                                                 batch, starts);

    // layer 1: aggregate x0 (width 192, edge-parallel) then GEMM 192->2048
    k_gather192<<<N_NODES, IN_STRIDE, 0, stream>>>(x0, indptr, ecol, ewgt, dinv, A1);
    k_mfma_gemm<<<16 * 80, 256, 0, stream>>>(A1, IN_STRIDE, N_NODES, W1t, IN_STRIDE, H1, b1f, 1, Hb, 16);

    // layer 2: GEMM 2048->1024, then XCD-sliced gather + bias + relu
    k_mfma_gemm<<<8 * 80, 256, 0, stream>>>(Hb, H1, N_NODES, W2t, H1, H2, nullptr, 0, Gb, 8);
    k_gather_slice<<<N_NODES * 8, 64, 0, stream>>>(Gb, indptr, ecol, ewgt, dinv, b2f, x2);

    // layer 3: GEMM 1024->1024, then XCD-sliced gather + bias + relu
    k_mfma_gemm<<<8 * 80, 256, 0, stream>>>(x2, H2, N_NODES, W3t, H2, H2, nullptr, 0, Gb, 8);
    k_gather_slice<<<N_NODES * 8, 64, 0, stream>>>(Gb, indptr, ecol, ewgt, dinv, b3f, x3);

    // pool partials; mean-normalize fused into head layer 1
    k_pool_part<<<dim3(NGRAPH * PCHUNK, H2 / 256), 256, 0, stream>>>(x3, starts, pacc);

    // MLP head: full-K fused per layer
    k_head_full_pool<<<64, 256, 0, stream>>>(pacc, starts, h1wt, d_in[12], hA, 1024, mode);
    k_head_full<<<64, 256, 0, stream>>>(hA, h2wt, d_in[14], hB, 1024, mode);
    k_head_full<<<32, 256, 0, stream>>>(hB, h3wt, d_in[16], hA, 512, mode);
    k_head_out<<<NGRAPH * NCLS, 64, 0, stream>>>(hA, d_in[17], d_in[18], d_out, mode);

    hipError_t e1 = hipGetLastError();
    if (e1 != hipSuccess) hipMemsetAsync(d_out, 0x47, 64, stream);
}